// Round 4
// baseline (395.037 us; speedup 1.0000x reference)
//
#include <hip/hip_runtime.h>
#include <hip/hip_bf16.h>
#include <math.h>

typedef short bf16x8 __attribute__((ext_vector_type(8)));
typedef float f32x4  __attribute__((ext_vector_type(4)));

constexpr int B_=4, CIN=96, H_=256, W_=256, HID=192, C2=384;
constexpr int NPX = H_*W_;          // 65536 px per plane
#define PB 8
constexpr int HP = H_/PB, WP = W_/PB;

__device__ __forceinline__ ushort f2bf(float f) {
    __hip_bfloat16 h = __float2bfloat16(f);
    ushort u; __builtin_memcpy(&u, &h, 2); return u;
}
__device__ __forceinline__ float bf2f(ushort u) {
    __hip_bfloat16 h; __builtin_memcpy(&h, &u, 2); return __bfloat162float(h);
}
// extract channel sub (0=lo,1=hi) of a packed bf16-pair uint as float
__device__ __forceinline__ float extc(uint u, int sub) {
    uint w = sub ? (u & 0xffff0000u) : (u << 16);
    float f; __builtin_memcpy(&f, &w, 4); return f;
}

// Fast exact-erf GELU: A&S 7.1.26 rational approx, |err| <= ~2e-7 abs.
__device__ __forceinline__ float gelu_f(float x) {
    float u  = x * 0.70710678118654752f;
    float au = fabsf(u);
    float t  = __builtin_amdgcn_rcpf(fmaf(0.3275911f, au, 1.0f));
    float poly = t * fmaf(t, fmaf(t, fmaf(t, fmaf(t, 1.061405429f,
                     -1.453152027f), 1.421413741f), -0.284496736f),
                     0.254829592f);
    float e  = __builtin_amdgcn_exp2f(au * au * -1.4426950408889634f);
    float g  = fmaf(-poly, e, 1.0f);          // erf(|u|)
    float one_plus = 1.0f + copysignf(g, u);  // 1 + erf(u)
    return 0.5f * x * one_plus;
}

// ---------------------------------------------------------------------------
// prep_gate: per-channel 8x8 spatial gate kernel from fft_w (+identity flags).
// ---------------------------------------------------------------------------
__global__ void prep_gate(const float* __restrict__ fftw,
                          float* __restrict__ g, int* __restrict__ flags) {
    int c = blockIdx.x;
    int t = threadIdx.x;             // one wave
    int n1 = t >> 3, n2 = t & 7;
    const float* Wc = fftw + c * 40;
    const double ct[8] = {1.0, 0.70710678118654752, 0.0, -0.70710678118654752,
                          -1.0, -0.70710678118654752, 0.0, 0.70710678118654752};
    double acc = 0.0;
    for (int k1 = 0; k1 < 8; ++k1)
        for (int k2 = 0; k2 < 8; ++k2) {
            double geff;
            if (k2 == 0 || k2 == 4)
                geff = 0.5 * ((double)Wc[k1*5+k2] + (double)Wc[((8-k1)&7)*5+k2]);
            else if (k2 < 4) geff = (double)Wc[k1*5+k2];
            else             geff = (double)Wc[((8-k1)&7)*5 + (8-k2)];
            acc += geff * ct[(k1*n1 + k2*n2) & 7];
        }
    acc *= (1.0/64.0);
    g[c*64 + t] = (float)acc;
    double expect = (t == 0) ? 1.0 : 0.0;
    unsigned long long m = __ballot(fabs(acc - expect) <= 1e-6);
    if (t == 0) flags[c] = (m == 0xFFFFFFFFFFFFFFFFull) ? 1 : 0;
}

__global__ void reduce_flags(const int* __restrict__ flags,
                             int* __restrict__ allflag) {
    int t = threadIdx.x;             // 64
    int ok = 1;
    for (int j = t; j < C2; j += 64) ok &= flags[j];
    unsigned long long m = __ballot(ok != 0);
    if (t == 0) allflag[0] = (m == 0xFFFFFFFFFFFFFFFFull) ? 1 : 0;
}

// ---------------------------------------------------------------------------
// prep_w: split weights into bf16 hi + lo (residual) pairs.
// ---------------------------------------------------------------------------
__global__ void prep_w(const float* __restrict__ w_in, const float* __restrict__ w_out,
                       ushort* __restrict__ whi_in,  ushort* __restrict__ wlo_in,
                       ushort* __restrict__ whi_out, ushort* __restrict__ wlo_out) {
    int idx = blockIdx.x * 256 + threadIdx.x;
    if (idx < C2*CIN) {
        float v = w_in[idx];
        ushort h = f2bf(v);
        whi_in[idx] = h;
        wlo_in[idx] = f2bf(v - bf2f(h));
    }
    int j = idx - C2*CIN;
    if (j >= 0 && j < CIN*HID) {
        float v = w_out[j];
        ushort h = f2bf(v);
        whi_out[j] = h;
        wlo_out[j] = f2bf(v - bf2f(h));
    }
}

// ---------------------------------------------------------------------------
// A1: GEMM1 via MFMA 16x16x32 bf16.  z[c][px] = sum_k w_in[c][k] * x[k][px]
// z stored as packed channel-pair uints: z4[cp][px] = bf16(2cp) | bf16(2cp+1)<<16
// Grid: (1024 px-blocks, nb batches).
// ---------------------------------------------------------------------------
__global__ __launch_bounds__(256)
void gemm1_mfma(const float* __restrict__ x,
                const ushort* __restrict__ whi, const ushort* __restrict__ wlo,
                uint* __restrict__ z4, int b0) {
    int t = threadIdx.x;
    int l = t & 63, wv = t >> 6;
    int lm = l & 15, g4 = l >> 4;
    int px0 = blockIdx.x * 64;
    int bg = blockIdx.y;
    const float* xb = x + (size_t)(b0 + bg) * CIN * NPX;
    uint* zb = z4 + (size_t)bg * HID * NPX;

    f32x4 acc[6][4];
#pragma unroll
    for (int mf = 0; mf < 6; ++mf)
#pragma unroll
        for (int nf = 0; nf < 4; ++nf) acc[mf][nf] = (f32x4){0.f,0.f,0.f,0.f};

#pragma unroll
    for (int kc = 0; kc < 3; ++kc) {
        int k0 = kc*32 + g4*8;
        bf16x8 bfr[4];
#pragma unroll
        for (int nf = 0; nf < 4; ++nf) {
            const float* xp = xb + (size_t)k0 * NPX + px0 + nf*16 + lm;
            bf16x8 v;
#pragma unroll
            for (int j = 0; j < 8; ++j) v[j] = (short)f2bf(xp[(size_t)j * NPX]);
            bfr[nf] = v;
        }
#pragma unroll
        for (int mf = 0; mf < 6; ++mf) {
            int row = wv*96 + mf*16 + lm;
            bf16x8 ah = *(const bf16x8*)(whi + (size_t)row*CIN + k0);
            bf16x8 al = *(const bf16x8*)(wlo + (size_t)row*CIN + k0);
#pragma unroll
            for (int nf = 0; nf < 4; ++nf) {
                acc[mf][nf] = __builtin_amdgcn_mfma_f32_16x16x32_bf16(ah, bfr[nf], acc[mf][nf], 0,0,0);
                acc[mf][nf] = __builtin_amdgcn_mfma_f32_16x16x32_bf16(al, bfr[nf], acc[mf][nf], 0,0,0);
            }
        }
    }
    // C/D: col = lane&15, row = g4*4 + r; rows are channels -> pack pairs
#pragma unroll
    for (int mf = 0; mf < 6; ++mf)
#pragma unroll
        for (int nf = 0; nf < 4; ++nf) {
            int px = px0 + nf*16 + lm;
            int basech = wv*96 + mf*16 + g4*4;
            int cp = basech >> 1;
            uint u01 = (uint)f2bf(acc[mf][nf][0]) | ((uint)f2bf(acc[mf][nf][1]) << 16);
            uint u23 = (uint)f2bf(acc[mf][nf][2]) | ((uint)f2bf(acc[mf][nf][3]) << 16);
            zb[(size_t)cp * NPX + px]       = u01;
            zb[(size_t)(cp+1) * NPX + px]   = u23;
        }
}

// ---------------------------------------------------------------------------
// A2: spectral-gate fixup on packed z. No-op when allflag (fft_w == ones).
// Grid: (1024 patches, nb).
// ---------------------------------------------------------------------------
__global__ __launch_bounds__(256)
void gate_fix(uint* __restrict__ z4, const float* __restrict__ g,
              const int* __restrict__ flags, const int* __restrict__ allflag) {
    if (allflag[0]) return;
    int pid = blockIdx.x;
    int bg = blockIdx.y;
    int ph = pid >> 5, pw = pid & 31;
    int t = threadIdx.x, l = t & 63, wv = t >> 6;
    int p1 = l >> 3, p2 = l & 7;
    uint* zb = z4 + (size_t)bg * HID * NPX;
    size_t base = (size_t)(ph*8) * W_ + pw*8;
    for (int cp = wv; cp < HID; cp += 4) {
        int f0 = flags[2*cp], f1 = flags[2*cp+1];
        if (f0 & f1) continue;
        const float* gc0 = g + (2*cp)*64;
        const float* gc1 = gc0 + 64;
        size_t zi = (size_t)cp * NPX + base + (size_t)p1 * W_ + p2;
        uint u = zb[zi];
        float v0 = extc(u, 0), v1 = extc(u, 1);
        float s0 = 0.f, s1 = 0.f;
        for (int q = 0; q < 64; ++q) {
            int idx = ((p1 - (q >> 3)) & 7)*8 + ((p2 - (q & 7)) & 7);
            s0 += __shfl(v0, q, 64) * gc0[idx];
            s1 += __shfl(v1, q, 64) * gc1[idx];
        }
        float r0 = f0 ? v0 : s0;
        float r1 = f1 ? v1 : s1;
        zb[zi] = (uint)f2bf(r0) | ((uint)f2bf(r1) << 16);
    }
}

// ---------------------------------------------------------------------------
// B1: depthwise 3x3 + fast GELU gating on packed z.
// Block: 512 thr; strip = 256 px x 8 rows; split = 8 tg-channels (4 packed
// planes each half).  T14 reg-prefetch staging; shfl column halo.
// Output in MFMA-B-frag layout: tgf[panel][kc][lane][8 bf16].
// Grid: (32 strips, 24 splits, nb).
// ---------------------------------------------------------------------------
__global__ __launch_bounds__(512)
void dw_gelu3(const uint* __restrict__ z4, const float* __restrict__ w_dw,
              ushort* __restrict__ tgf) {
    __shared__ uint sZ[2][10][264];       // [half][halo row][4+256+4]
    int t = threadIdx.x;
    int wv = t >> 6;                      // 0..7 output row in strip
    int lane = t & 63;
    int cb = lane * 4;                    // 4 px per thread
    int strip = blockIdx.x;
    int s = blockIdx.y;                   // split: tg channels 8s..8s+7
    int bg = blockIdx.z;
    int row0 = strip * 8;
    int gy = row0 + wv;
    int p0 = s * 4;                       // packed plane base (half0)
    const uint* zb = z4 + (size_t)bg * HID * NPX;
    ushort* tb = tgf + (size_t)bg * HID * NPX;

    for (int i = t; i < 2*10*264; i += 512) ((uint*)sZ)[i] = 0u;
    __syncthreads();

    uint4 pr[3]; int pv[3];
    auto prefetch = [&](int i) {
#pragma unroll
        for (int it = 0; it < 3; ++it) {
            int v = t + it*512;
            pv[it] = 0;
            if (v < 1280) {
                int half = (v >= 640) ? 1 : 0;
                int rem = v - half*640;
                int row = rem >> 6;
                int vx = rem & 63;
                int y = row0 - 1 + row;
                if (y >= 0 && y < H_) {
                    pr[it] = *(const uint4*)(zb + (size_t)(half*96 + p0 + i)*NPX
                                             + (size_t)y*W_ + vx*4);
                    pv[it] = 1;
                }
            }
        }
    };
    auto write_lds = [&]() {
#pragma unroll
        for (int it = 0; it < 3; ++it) {
            int v = t + it*512;
            if (v < 1280 && pv[it]) {
                int half = (v >= 640) ? 1 : 0;
                int rem = v - half*640;
                int row = rem >> 6;
                int vx = rem & 63;
                *(uint4*)&sZ[half][row][4 + vx*4] = pr[it];
            }
        }
    };

    prefetch(0);
    uint pk[4][4];
#pragma unroll
    for (int i = 0; i < 4; ++i) {
        write_lds();
        __syncthreads();
        if (i < 3) prefetch(i + 1);       // overlaps compute below (T14)

        int c_e = s*8 + 2*i;              // even tg channel of this plane
        const float* wA0 = w_dw + (size_t)c_e * 9;
        const float* wA1 = wA0 + 9;
        const float* wB0 = w_dw + (size_t)(c_e + HID) * 9;
        const float* wB1 = wB0 + 9;

        float d1[2][4] = {{0,0,0,0},{0,0,0,0}};
        float d2[2][4] = {{0,0,0,0},{0,0,0,0}};
#pragma unroll
        for (int dr = 0; dr < 3; ++dr) {
            int r = wv + dr;
            uint4 aM = *(const uint4*)&sZ[0][r][4 + cb];
            uint4 bM = *(const uint4*)&sZ[1][r][4 + cb];
            uint aLh = sZ[0][r][3],  aRh = sZ[0][r][260];
            uint bLh = sZ[1][r][3],  bRh = sZ[1][r][260];
            uint aL = (uint)__shfl_up((int)aM.w, 1, 64);  if (lane == 0)  aL = aLh;
            uint aR = (uint)__shfl_down((int)aM.x, 1, 64); if (lane == 63) aR = aRh;
            uint bL = (uint)__shfl_up((int)bM.w, 1, 64);  if (lane == 0)  bL = bLh;
            uint bR = (uint)__shfl_down((int)bM.x, 1, 64); if (lane == 63) bR = bRh;
#pragma unroll
            for (int sub = 0; sub < 2; ++sub) {
                const float* w1 = sub ? wA1 : wA0;
                const float* w2 = sub ? wB1 : wB0;
                float x0 = extc(aL, sub),  x1 = extc(aM.x, sub), x2 = extc(aM.y, sub);
                float x3 = extc(aM.z, sub), x4 = extc(aM.w, sub), x5 = extc(aR, sub);
                float u0 = w1[dr*3+0], u1 = w1[dr*3+1], u2 = w1[dr*3+2];
                d1[sub][0] = fmaf(x0,u0, fmaf(x1,u1, fmaf(x2,u2, d1[sub][0])));
                d1[sub][1] = fmaf(x1,u0, fmaf(x2,u1, fmaf(x3,u2, d1[sub][1])));
                d1[sub][2] = fmaf(x2,u0, fmaf(x3,u1, fmaf(x4,u2, d1[sub][2])));
                d1[sub][3] = fmaf(x3,u0, fmaf(x4,u1, fmaf(x5,u2, d1[sub][3])));
                float y0 = extc(bL, sub),  y1 = extc(bM.x, sub), y2 = extc(bM.y, sub);
                float y3 = extc(bM.z, sub), y4 = extc(bM.w, sub), y5 = extc(bR, sub);
                float v0 = w2[dr*3+0], v1 = w2[dr*3+1], v2 = w2[dr*3+2];
                d2[sub][0] = fmaf(y0,v0, fmaf(y1,v1, fmaf(y2,v2, d2[sub][0])));
                d2[sub][1] = fmaf(y1,v0, fmaf(y2,v1, fmaf(y3,v2, d2[sub][1])));
                d2[sub][2] = fmaf(y2,v0, fmaf(y3,v1, fmaf(y4,v2, d2[sub][2])));
                d2[sub][3] = fmaf(y3,v0, fmaf(y4,v1, fmaf(y5,v2, d2[sub][3])));
            }
        }
#pragma unroll
        for (int sub = 0; sub < 2; ++sub)
#pragma unroll
            for (int j = 0; j < 4; ++j) {
                ushort u = f2bf(gelu_f(d1[sub][j]) * d2[sub][j]);
                if (sub == 0) pk[j][i] = (uint)u;
                else          pk[j][i] |= ((uint)u) << 16;
            }
        __syncthreads();
    }

    int kc = s >> 2, gg = s & 3;
#pragma unroll
    for (int j = 0; j < 4; ++j) {
        int pidx = gy * W_ + cb + j;
        int panel = pidx >> 4, lm = pidx & 15;
        uint4 val; val.x = pk[j][0]; val.y = pk[j][1];
        val.z = pk[j][2]; val.w = pk[j][3];
        *(uint4*)(tb + (size_t)((panel*6 + kc)*64 + gg*16 + lm) * 8) = val;
    }
}

// ---------------------------------------------------------------------------
// B2: GEMM2 via MFMA, all 96 oc per block (tgf read once).
// Grid: (256 rows, 1, nb); wave owns 64 px.
// ---------------------------------------------------------------------------
__global__ __launch_bounds__(256)
void gemm2_mfma(const ushort* __restrict__ tgf,
                const ushort* __restrict__ whi, const ushort* __restrict__ wlo,
                float* __restrict__ out, int b0) {
    int t = threadIdx.x;
    int l = t & 63, wv = t >> 6;
    int lm = l & 15, g4 = l >> 4;
    int h = blockIdx.x;
    int bg = blockIdx.z;
    int px0 = h * W_ + wv*64;
    int prel0 = h*16 + wv*4;
    const ushort* tb = tgf + (size_t)bg * HID * NPX;

    f32x4 acc[6][4];
#pragma unroll
    for (int mf = 0; mf < 6; ++mf)
#pragma unroll
        for (int nf = 0; nf < 4; ++nf) acc[mf][nf] = (f32x4){0.f,0.f,0.f,0.f};

#pragma unroll
    for (int kc = 0; kc < 6; ++kc) {
        bf16x8 bfr[4];
#pragma unroll
        for (int nf = 0; nf < 4; ++nf)
            bfr[nf] = *(const bf16x8*)(tb + (size_t)(((prel0+nf)*6 + kc)*64 + l) * 8);
        int k0 = kc*32 + g4*8;
#pragma unroll
        for (int mf = 0; mf < 6; ++mf) {
            int row = mf*16 + lm;
            bf16x8 ah = *(const bf16x8*)(whi + (size_t)row*HID + k0);
            bf16x8 al = *(const bf16x8*)(wlo + (size_t)row*HID + k0);
#pragma unroll
            for (int nf = 0; nf < 4; ++nf) {
                acc[mf][nf] = __builtin_amdgcn_mfma_f32_16x16x32_bf16(ah, bfr[nf], acc[mf][nf], 0,0,0);
                acc[mf][nf] = __builtin_amdgcn_mfma_f32_16x16x32_bf16(al, bfr[nf], acc[mf][nf], 0,0,0);
            }
        }
    }
    float* ob = out + (size_t)(b0 + bg) * CIN * NPX;
#pragma unroll
    for (int mf = 0; mf < 6; ++mf)
#pragma unroll
        for (int nf = 0; nf < 4; ++nf)
#pragma unroll
            for (int r = 0; r < 4; ++r) {
                int oc = mf*16 + g4*4 + r;
                ob[(size_t)oc * NPX + px0 + nf*16 + lm] = acc[mf][nf][r];
            }
}

// ---------------------------------------------------------------------------
extern "C" void kernel_launch(void* const* d_in, const int* in_sizes, int n_in,
                              void* d_out, int out_size, void* d_ws, size_t ws_size,
                              hipStream_t stream) {
    const float* x     = (const float*)d_in[0];
    const float* w_in  = (const float*)d_in[1];
    const float* w_dw  = (const float*)d_in[2];
    const float* fftw  = (const float*)d_in[3];
    const float* w_out = (const float*)d_in[4];
    float* out = (float*)d_out;

    char* ws = (char*)d_ws;
    ushort* whi_in  = (ushort*)(ws + 0);        //  73728
    ushort* wlo_in  = (ushort*)(ws + 73728);    //  73728
    ushort* whi_out = (ushort*)(ws + 147456);   //  36864
    ushort* wlo_out = (ushort*)(ws + 184320);   //  36864
    float*  g       = (float*) (ws + 221184);   //  98304
    int*    flags   = (int*)   (ws + 319488);   //   1536
    int*    allflag = (int*)   (ws + 321024);   //      4

    const size_t zoff   = 327680;
    const size_t zbytes = (size_t)HID * NPX * 4;   // 50331648 per batch (packed)
    const size_t tbytes = (size_t)HID * NPX * 2;   // 25165824 per batch
    size_t avail = (ws_size > zoff) ? ws_size - zoff : 0;
    int nbg = (int)(avail / (zbytes + tbytes));
    if (nbg < 1) nbg = 1;
    if (nbg > B_) nbg = B_;
    uint*   z4  = (uint*)(ws + zoff);
    ushort* tgf = (ushort*)(ws + zoff + (size_t)nbg * zbytes);

    prep_gate<<<dim3(C2), dim3(64), 0, stream>>>(fftw, g, flags);
    reduce_flags<<<dim3(1), dim3(64), 0, stream>>>(flags, allflag);
    prep_w<<<dim3(216), dim3(256), 0, stream>>>(w_in, w_out,
                                                whi_in, wlo_in, whi_out, wlo_out);

    for (int b0 = 0; b0 < B_; b0 += nbg) {
        int nb = (B_ - b0 < nbg) ? (B_ - b0) : nbg;
        gemm1_mfma<<<dim3(NPX/64, nb), dim3(256), 0, stream>>>(x, whi_in, wlo_in, z4, b0);
        gate_fix<<<dim3(HP*WP, nb), dim3(256), 0, stream>>>(z4, g, flags, allflag);
        dw_gelu3<<<dim3(32, 24, nb), dim3(512), 0, stream>>>(z4, w_dw, tgf);
        gemm2_mfma<<<dim3(H_, 1, nb), dim3(256), 0, stream>>>(tgf, whi_out, wlo_out, out, b0);
    }
}

// Round 5
// 381.021 us; speedup vs baseline: 1.0368x; 1.0368x over previous
//
#include <hip/hip_runtime.h>
#include <hip/hip_bf16.h>
#include <math.h>

typedef short bf16x8 __attribute__((ext_vector_type(8)));
typedef float f32x4  __attribute__((ext_vector_type(4)));

constexpr int B_=4, CIN=96, H_=256, W_=256, HID=192, C2=384;
constexpr int NPX = H_*W_;          // 65536 px per plane
#define PB 8
constexpr int HP = H_/PB, WP = W_/PB;

__device__ __forceinline__ ushort f2bf(float f) {
    __hip_bfloat16 h = __float2bfloat16(f);
    ushort u; __builtin_memcpy(&u, &h, 2); return u;
}
__device__ __forceinline__ float bf2f(ushort u) {
    __hip_bfloat16 h; __builtin_memcpy(&h, &u, 2); return __bfloat162float(h);
}
// extract channel sub (0=lo,1=hi) of a packed bf16-pair uint as float
__device__ __forceinline__ float extc(uint u, int sub) {
    uint w = sub ? (u & 0xffff0000u) : (u << 16);
    float f; __builtin_memcpy(&f, &w, 4); return f;
}

// Fast exact-erf GELU: A&S 7.1.26 rational approx, |err| <= ~2e-7 abs.
__device__ __forceinline__ float gelu_f(float x) {
    float u  = x * 0.70710678118654752f;
    float au = fabsf(u);
    float t  = __builtin_amdgcn_rcpf(fmaf(0.3275911f, au, 1.0f));
    float poly = t * fmaf(t, fmaf(t, fmaf(t, fmaf(t, 1.061405429f,
                     -1.453152027f), 1.421413741f), -0.284496736f),
                     0.254829592f);
    float e  = __builtin_amdgcn_exp2f(au * au * -1.4426950408889634f);
    float g  = fmaf(-poly, e, 1.0f);          // erf(|u|)
    float one_plus = 1.0f + copysignf(g, u);  // 1 + erf(u)
    return 0.5f * x * one_plus;
}

// ---------------------------------------------------------------------------
// prep_gate: per-channel 8x8 spatial gate kernel from fft_w (+identity flags).
// ---------------------------------------------------------------------------
__global__ void prep_gate(const float* __restrict__ fftw,
                          float* __restrict__ g, int* __restrict__ flags) {
    int c = blockIdx.x;
    int t = threadIdx.x;             // one wave
    int n1 = t >> 3, n2 = t & 7;
    const float* Wc = fftw + c * 40;
    const double ct[8] = {1.0, 0.70710678118654752, 0.0, -0.70710678118654752,
                          -1.0, -0.70710678118654752, 0.0, 0.70710678118654752};
    double acc = 0.0;
    for (int k1 = 0; k1 < 8; ++k1)
        for (int k2 = 0; k2 < 8; ++k2) {
            double geff;
            if (k2 == 0 || k2 == 4)
                geff = 0.5 * ((double)Wc[k1*5+k2] + (double)Wc[((8-k1)&7)*5+k2]);
            else if (k2 < 4) geff = (double)Wc[k1*5+k2];
            else             geff = (double)Wc[((8-k1)&7)*5 + (8-k2)];
            acc += geff * ct[(k1*n1 + k2*n2) & 7];
        }
    acc *= (1.0/64.0);
    g[c*64 + t] = (float)acc;
    double expect = (t == 0) ? 1.0 : 0.0;
    unsigned long long m = __ballot(fabs(acc - expect) <= 1e-6);
    if (t == 0) flags[c] = (m == 0xFFFFFFFFFFFFFFFFull) ? 1 : 0;
}

__global__ void reduce_flags(const int* __restrict__ flags,
                             int* __restrict__ allflag) {
    int t = threadIdx.x;             // 64
    int ok = 1;
    for (int j = t; j < C2; j += 64) ok &= flags[j];
    unsigned long long m = __ballot(ok != 0);
    if (t == 0) allflag[0] = (m == 0xFFFFFFFFFFFFFFFFull) ? 1 : 0;
}

// ---------------------------------------------------------------------------
// prep_w: split weights into bf16 hi + lo (residual) pairs.
// ---------------------------------------------------------------------------
__global__ void prep_w(const float* __restrict__ w_in, const float* __restrict__ w_out,
                       ushort* __restrict__ whi_in,  ushort* __restrict__ wlo_in,
                       ushort* __restrict__ whi_out, ushort* __restrict__ wlo_out) {
    int idx = blockIdx.x * 256 + threadIdx.x;
    if (idx < C2*CIN) {
        float v = w_in[idx];
        ushort h = f2bf(v);
        whi_in[idx] = h;
        wlo_in[idx] = f2bf(v - bf2f(h));
    }
    int j = idx - C2*CIN;
    if (j >= 0 && j < CIN*HID) {
        float v = w_out[j];
        ushort h = f2bf(v);
        whi_out[j] = h;
        wlo_out[j] = f2bf(v - bf2f(h));
    }
}

// ---------------------------------------------------------------------------
// A1: GEMM1 via MFMA 16x16x32 bf16.  z[c][px] = sum_k w_in[c][k] * x[k][px]
// z stored as packed channel-pair uints: z4[cp][px] = bf16(2cp) | bf16(2cp+1)<<16
// ---------------------------------------------------------------------------
__global__ __launch_bounds__(256)
void gemm1_mfma(const float* __restrict__ x,
                const ushort* __restrict__ whi, const ushort* __restrict__ wlo,
                uint* __restrict__ z4, int b0) {
    int t = threadIdx.x;
    int l = t & 63, wv = t >> 6;
    int lm = l & 15, g4 = l >> 4;
    int px0 = blockIdx.x * 64;
    int bg = blockIdx.y;
    const float* xb = x + (size_t)(b0 + bg) * CIN * NPX;
    uint* zb = z4 + (size_t)bg * HID * NPX;

    f32x4 acc[6][4];
#pragma unroll
    for (int mf = 0; mf < 6; ++mf)
#pragma unroll
        for (int nf = 0; nf < 4; ++nf) acc[mf][nf] = (f32x4){0.f,0.f,0.f,0.f};

#pragma unroll
    for (int kc = 0; kc < 3; ++kc) {
        int k0 = kc*32 + g4*8;
        bf16x8 bfr[4];
#pragma unroll
        for (int nf = 0; nf < 4; ++nf) {
            const float* xp = xb + (size_t)k0 * NPX + px0 + nf*16 + lm;
            bf16x8 v;
#pragma unroll
            for (int j = 0; j < 8; ++j) v[j] = (short)f2bf(xp[(size_t)j * NPX]);
            bfr[nf] = v;
        }
#pragma unroll
        for (int mf = 0; mf < 6; ++mf) {
            int row = wv*96 + mf*16 + lm;
            bf16x8 ah = *(const bf16x8*)(whi + (size_t)row*CIN + k0);
            bf16x8 al = *(const bf16x8*)(wlo + (size_t)row*CIN + k0);
#pragma unroll
            for (int nf = 0; nf < 4; ++nf) {
                acc[mf][nf] = __builtin_amdgcn_mfma_f32_16x16x32_bf16(ah, bfr[nf], acc[mf][nf], 0,0,0);
                acc[mf][nf] = __builtin_amdgcn_mfma_f32_16x16x32_bf16(al, bfr[nf], acc[mf][nf], 0,0,0);
            }
        }
    }
#pragma unroll
    for (int mf = 0; mf < 6; ++mf)
#pragma unroll
        for (int nf = 0; nf < 4; ++nf) {
            int px = px0 + nf*16 + lm;
            int basech = wv*96 + mf*16 + g4*4;
            int cp = basech >> 1;
            uint u01 = (uint)f2bf(acc[mf][nf][0]) | ((uint)f2bf(acc[mf][nf][1]) << 16);
            uint u23 = (uint)f2bf(acc[mf][nf][2]) | ((uint)f2bf(acc[mf][nf][3]) << 16);
            zb[(size_t)cp * NPX + px]       = u01;
            zb[(size_t)(cp+1) * NPX + px]   = u23;
        }
}

// ---------------------------------------------------------------------------
// A2: spectral-gate fixup on packed z. No-op when allflag (fft_w == ones).
// ---------------------------------------------------------------------------
__global__ __launch_bounds__(256)
void gate_fix(uint* __restrict__ z4, const float* __restrict__ g,
              const int* __restrict__ flags, const int* __restrict__ allflag) {
    if (allflag[0]) return;
    int pid = blockIdx.x;
    int bg = blockIdx.y;
    int ph = pid >> 5, pw = pid & 31;
    int t = threadIdx.x, l = t & 63, wv = t >> 6;
    int p1 = l >> 3, p2 = l & 7;
    uint* zb = z4 + (size_t)bg * HID * NPX;
    size_t base = (size_t)(ph*8) * W_ + pw*8;
    for (int cp = wv; cp < HID; cp += 4) {
        int f0 = flags[2*cp], f1 = flags[2*cp+1];
        if (f0 & f1) continue;
        const float* gc0 = g + (2*cp)*64;
        const float* gc1 = gc0 + 64;
        size_t zi = (size_t)cp * NPX + base + (size_t)p1 * W_ + p2;
        uint u = zb[zi];
        float v0 = extc(u, 0), v1 = extc(u, 1);
        float s0 = 0.f, s1 = 0.f;
        for (int q = 0; q < 64; ++q) {
            int idx = ((p1 - (q >> 3)) & 7)*8 + ((p2 - (q & 7)) & 7);
            s0 += __shfl(v0, q, 64) * gc0[idx];
            s1 += __shfl(v1, q, 64) * gc1[idx];
        }
        float r0 = f0 ? v0 : s0;
        float r1 = f1 ? v1 : s1;
        zb[zi] = (uint)f2bf(r0) | ((uint)f2bf(r1) << 16);
    }
}

// ---------------------------------------------------------------------------
// B1 v3: barrier-free streaming depthwise 3x3 + GELU gating.
// Wave = 256-px row x 8-row strip x one packed plane-pair, rolling 3-row
// register pipeline, depth-1 row prefetch, shfl column halo. No LDS.
// 4 plane-pair iterations cover tg channels 8*jg..8*jg+7.
// Output directly in MFMA-B-frag layout (4B per px per pair).
// Grid: (8 strip-groups, 24 jg, nb); block = 256 = 4 waves = 4 strips.
// ---------------------------------------------------------------------------
__global__ __launch_bounds__(256)
void dw_gelu4(const uint* __restrict__ z4, const float* __restrict__ w_dw,
              ushort* __restrict__ tgf) {
    int t = threadIdx.x;
    int wv = t >> 6, lane = t & 63;
    int strip = blockIdx.x * 4 + wv;       // 0..31
    int jg = blockIdx.y;                   // 0..23
    int bg = blockIdx.z;
    int row0 = strip * 8;
    int cb = lane * 4;
    const uint* zb = z4 + (size_t)bg * HID * NPX;
    ushort* tb = tgf + (size_t)bg * HID * NPX;
    int kc = jg >> 2, gg = jg & 3;

#pragma unroll
    for (int pp = 0; pp < 4; ++pp) {
        int c  = jg*8 + pp*2;              // z1 channels c, c+1 (plane p1)
        int p1 = c >> 1;
        int p2 = p1 + 96;                  // z2 channels c+192, c+193
        // wave-uniform weights -> scalar regs
        float wA[18], wB[18];
#pragma unroll
        for (int k = 0; k < 18; ++k) {
            wA[k] = w_dw[(size_t)c*9 + k];
            wB[k] = w_dw[(size_t)(c+HID)*9 + k];
        }

        float accA[2][2][4], accB[2][2][4];   // [src][sub][px]
#pragma unroll
        for (int s = 0; s < 2; ++s)
#pragma unroll
            for (int u = 0; u < 2; ++u)
#pragma unroll
                for (int j = 0; j < 4; ++j) { accA[s][u][j]=0.f; accB[s][u][j]=0.f; }

        auto ld = [&](int r, uint4& A, uint4& B) {
            int y = row0 - 1 + r;
            A = (uint4){0,0,0,0}; B = (uint4){0,0,0,0};
            if (y >= 0 && y < H_) {
                A = *(const uint4*)(zb + (size_t)p1*NPX + (size_t)y*W_ + cb);
                B = *(const uint4*)(zb + (size_t)p2*NPX + (size_t)y*W_ + cb);
            }
        };

        uint4 a_cur, b_cur;
        ld(0, a_cur, b_cur);
#pragma unroll
        for (int r = 0; r < 10; ++r) {
            uint4 a_nxt, b_nxt;
            if (r < 9) ld(r + 1, a_nxt, b_nxt);

            uint aL = (uint)__shfl_up((int)a_cur.w, 1, 64);  if (lane == 0)  aL = 0u;
            uint aR = (uint)__shfl_down((int)a_cur.x, 1, 64); if (lane == 63) aR = 0u;
            uint bL = (uint)__shfl_up((int)b_cur.w, 1, 64);  if (lane == 0)  bL = 0u;
            uint bR = (uint)__shfl_down((int)b_cur.x, 1, 64); if (lane == 63) bR = 0u;

            float dA[2][4], dB[2][4];
#pragma unroll
            for (int sub = 0; sub < 2; ++sub) {
                {   // src A (z1)
                    float xv[6] = {extc(aL,sub), extc(a_cur.x,sub), extc(a_cur.y,sub),
                                   extc(a_cur.z,sub), extc(a_cur.w,sub), extc(aR,sub)};
                    const float* w = &wA[sub*9];
#pragma unroll
                    for (int j = 0; j < 4; ++j) {
                        float h2 = fmaf(xv[j],w[6], fmaf(xv[j+1],w[7], xv[j+2]*w[8]));
                        float h1 = fmaf(xv[j],w[3], fmaf(xv[j+1],w[4], xv[j+2]*w[5]));
                        float h0 = fmaf(xv[j],w[0], fmaf(xv[j+1],w[1], xv[j+2]*w[2]));
                        dA[sub][j]    = accA[0][sub][j] + h2;
                        accA[0][sub][j] = accB[0][sub][j] + h1;
                        accB[0][sub][j] = h0;
                    }
                }
                {   // src B (z2)
                    float xv[6] = {extc(bL,sub), extc(b_cur.x,sub), extc(b_cur.y,sub),
                                   extc(b_cur.z,sub), extc(b_cur.w,sub), extc(bR,sub)};
                    const float* w = &wB[sub*9];
#pragma unroll
                    for (int j = 0; j < 4; ++j) {
                        float h2 = fmaf(xv[j],w[6], fmaf(xv[j+1],w[7], xv[j+2]*w[8]));
                        float h1 = fmaf(xv[j],w[3], fmaf(xv[j+1],w[4], xv[j+2]*w[5]));
                        float h0 = fmaf(xv[j],w[0], fmaf(xv[j+1],w[1], xv[j+2]*w[2]));
                        dB[sub][j]    = accA[1][sub][j] + h2;
                        accA[1][sub][j] = accB[1][sub][j] + h1;
                        accB[1][sub][j] = h0;
                    }
                }
            }

            if (r >= 2) {
                int o = row0 + r - 2;
#pragma unroll
                for (int j = 0; j < 4; ++j) {
                    uint u = (uint)f2bf(gelu_f(dA[0][j]) * dB[0][j]) |
                             (((uint)f2bf(gelu_f(dA[1][j]) * dB[1][j])) << 16);
                    int pidx = o * W_ + cb + j;
                    int panel = pidx >> 4, lm = pidx & 15;
                    *(uint*)(tb + ((size_t)((panel*6 + kc)*64 + gg*16 + lm))*8 + pp*2) = u;
                }
            }
            a_cur = a_nxt; b_cur = b_nxt;
        }
    }
}

// ---------------------------------------------------------------------------
// B2: GEMM2 via MFMA, all 96 oc per block (tgf read once).
// ---------------------------------------------------------------------------
__global__ __launch_bounds__(256)
void gemm2_mfma(const ushort* __restrict__ tgf,
                const ushort* __restrict__ whi, const ushort* __restrict__ wlo,
                float* __restrict__ out, int b0) {
    int t = threadIdx.x;
    int l = t & 63, wv = t >> 6;
    int lm = l & 15, g4 = l >> 4;
    int h = blockIdx.x;
    int bg = blockIdx.z;
    int px0 = h * W_ + wv*64;
    int prel0 = h*16 + wv*4;
    const ushort* tb = tgf + (size_t)bg * HID * NPX;

    f32x4 acc[6][4];
#pragma unroll
    for (int mf = 0; mf < 6; ++mf)
#pragma unroll
        for (int nf = 0; nf < 4; ++nf) acc[mf][nf] = (f32x4){0.f,0.f,0.f,0.f};

#pragma unroll
    for (int kc = 0; kc < 6; ++kc) {
        bf16x8 bfr[4];
#pragma unroll
        for (int nf = 0; nf < 4; ++nf)
            bfr[nf] = *(const bf16x8*)(tb + (size_t)(((prel0+nf)*6 + kc)*64 + l) * 8);
        int k0 = kc*32 + g4*8;
#pragma unroll
        for (int mf = 0; mf < 6; ++mf) {
            int row = mf*16 + lm;
            bf16x8 ah = *(const bf16x8*)(whi + (size_t)row*HID + k0);
            bf16x8 al = *(const bf16x8*)(wlo + (size_t)row*HID + k0);
#pragma unroll
            for (int nf = 0; nf < 4; ++nf) {
                acc[mf][nf] = __builtin_amdgcn_mfma_f32_16x16x32_bf16(ah, bfr[nf], acc[mf][nf], 0,0,0);
                acc[mf][nf] = __builtin_amdgcn_mfma_f32_16x16x32_bf16(al, bfr[nf], acc[mf][nf], 0,0,0);
            }
        }
    }
    float* ob = out + (size_t)(b0 + bg) * CIN * NPX;
#pragma unroll
    for (int mf = 0; mf < 6; ++mf)
#pragma unroll
        for (int nf = 0; nf < 4; ++nf)
#pragma unroll
            for (int r = 0; r < 4; ++r) {
                int oc = mf*16 + g4*4 + r;
                ob[(size_t)oc * NPX + px0 + nf*16 + lm] = acc[mf][nf][r];
            }
}

// ---------------------------------------------------------------------------
extern "C" void kernel_launch(void* const* d_in, const int* in_sizes, int n_in,
                              void* d_out, int out_size, void* d_ws, size_t ws_size,
                              hipStream_t stream) {
    const float* x     = (const float*)d_in[0];
    const float* w_in  = (const float*)d_in[1];
    const float* w_dw  = (const float*)d_in[2];
    const float* fftw  = (const float*)d_in[3];
    const float* w_out = (const float*)d_in[4];
    float* out = (float*)d_out;

    char* ws = (char*)d_ws;
    ushort* whi_in  = (ushort*)(ws + 0);        //  73728
    ushort* wlo_in  = (ushort*)(ws + 73728);    //  73728
    ushort* whi_out = (ushort*)(ws + 147456);   //  36864
    ushort* wlo_out = (ushort*)(ws + 184320);   //  36864
    float*  g       = (float*) (ws + 221184);   //  98304
    int*    flags   = (int*)   (ws + 319488);   //   1536
    int*    allflag = (int*)   (ws + 321024);   //      4

    const size_t zoff   = 327680;
    const size_t zbytes = (size_t)HID * NPX * 4;   // 50331648 per batch (packed)
    const size_t tbytes = (size_t)HID * NPX * 2;   // 25165824 per batch
    size_t avail = (ws_size > zoff) ? ws_size - zoff : 0;
    int nbg = (int)(avail / (zbytes + tbytes));
    if (nbg < 1) nbg = 1;
    if (nbg > B_) nbg = B_;
    uint*   z4  = (uint*)(ws + zoff);
    ushort* tgf = (ushort*)(ws + zoff + (size_t)nbg * zbytes);

    prep_gate<<<dim3(C2), dim3(64), 0, stream>>>(fftw, g, flags);
    reduce_flags<<<dim3(1), dim3(64), 0, stream>>>(flags, allflag);
    prep_w<<<dim3(216), dim3(256), 0, stream>>>(w_in, w_out,
                                                whi_in, wlo_in, whi_out, wlo_out);

    for (int b0 = 0; b0 < B_; b0 += nbg) {
        int nb = (B_ - b0 < nbg) ? (B_ - b0) : nbg;
        gemm1_mfma<<<dim3(NPX/64, nb), dim3(256), 0, stream>>>(x, whi_in, wlo_in, z4, b0);
        gate_fix<<<dim3(HP*WP, nb), dim3(256), 0, stream>>>(z4, g, flags, allflag);
        dw_gelu4<<<dim3(8, 24, nb), dim3(256), 0, stream>>>(z4, w_dw, tgf);
        gemm2_mfma<<<dim3(H_, 1, nb), dim3(256), 0, stream>>>(tgf, whi_out, wlo_out, out, b0);
    }
}

// Round 6
// 249.701 us; speedup vs baseline: 1.5820x; 1.5259x over previous
//
#include <hip/hip_runtime.h>
#include <hip/hip_bf16.h>
#include <math.h>

typedef short bf16x8 __attribute__((ext_vector_type(8)));
typedef float f32x4  __attribute__((ext_vector_type(4)));

constexpr int B_=4, CIN=96, H_=256, W_=256, HID=192, C2=384;
constexpr int NPX = H_*W_;          // 65536 px per plane
#define PB 8
constexpr int HP = H_/PB, WP = W_/PB;

__device__ __forceinline__ ushort f2bf(float f) {
    __hip_bfloat16 h = __float2bfloat16(f);
    ushort u; __builtin_memcpy(&u, &h, 2); return u;
}
__device__ __forceinline__ float bf2f(ushort u) {
    __hip_bfloat16 h; __builtin_memcpy(&h, &u, 2); return __bfloat162float(h);
}
// extract channel sub (0=lo,1=hi) of a packed bf16-pair uint as float
__device__ __forceinline__ float extc(uint u, int sub) {
    uint w = sub ? (u & 0xffff0000u) : (u << 16);
    float f; __builtin_memcpy(&f, &w, 4); return f;
}

// Fast exact-erf GELU: A&S 7.1.26 rational approx, |err| <= ~2e-7 abs.
__device__ __forceinline__ float gelu_f(float x) {
    float u  = x * 0.70710678118654752f;
    float au = fabsf(u);
    float t  = __builtin_amdgcn_rcpf(fmaf(0.3275911f, au, 1.0f));
    float poly = t * fmaf(t, fmaf(t, fmaf(t, fmaf(t, 1.061405429f,
                     -1.453152027f), 1.421413741f), -0.284496736f),
                     0.254829592f);
    float e  = __builtin_amdgcn_exp2f(au * au * -1.4426950408889634f);
    float g  = fmaf(-poly, e, 1.0f);          // erf(|u|)
    float one_plus = 1.0f + copysignf(g, u);  // 1 + erf(u)
    return 0.5f * x * one_plus;
}

// ---------------------------------------------------------------------------
// prep_gate: per-channel 8x8 spatial gate kernel from fft_w (+identity flags).
// ---------------------------------------------------------------------------
__global__ void prep_gate(const float* __restrict__ fftw,
                          float* __restrict__ g, int* __restrict__ flags) {
    int c = blockIdx.x;
    int t = threadIdx.x;             // one wave
    int n1 = t >> 3, n2 = t & 7;
    const float* Wc = fftw + c * 40;
    const double ct[8] = {1.0, 0.70710678118654752, 0.0, -0.70710678118654752,
                          -1.0, -0.70710678118654752, 0.0, 0.70710678118654752};
    double acc = 0.0;
    for (int k1 = 0; k1 < 8; ++k1)
        for (int k2 = 0; k2 < 8; ++k2) {
            double geff;
            if (k2 == 0 || k2 == 4)
                geff = 0.5 * ((double)Wc[k1*5+k2] + (double)Wc[((8-k1)&7)*5+k2]);
            else if (k2 < 4) geff = (double)Wc[k1*5+k2];
            else             geff = (double)Wc[((8-k1)&7)*5 + (8-k2)];
            acc += geff * ct[(k1*n1 + k2*n2) & 7];
        }
    acc *= (1.0/64.0);
    g[c*64 + t] = (float)acc;
    double expect = (t == 0) ? 1.0 : 0.0;
    unsigned long long m = __ballot(fabs(acc - expect) <= 1e-6);
    if (t == 0) flags[c] = (m == 0xFFFFFFFFFFFFFFFFull) ? 1 : 0;
}

__global__ void reduce_flags(const int* __restrict__ flags,
                             int* __restrict__ allflag) {
    int t = threadIdx.x;             // 64
    int ok = 1;
    for (int j = t; j < C2; j += 64) ok &= flags[j];
    unsigned long long m = __ballot(ok != 0);
    if (t == 0) allflag[0] = (m == 0xFFFFFFFFFFFFFFFFull) ? 1 : 0;
}

// ---------------------------------------------------------------------------
// prep_w: split weights into bf16 hi + lo (residual) pairs.
// ---------------------------------------------------------------------------
__global__ void prep_w(const float* __restrict__ w_in, const float* __restrict__ w_out,
                       ushort* __restrict__ whi_in,  ushort* __restrict__ wlo_in,
                       ushort* __restrict__ whi_out, ushort* __restrict__ wlo_out) {
    int idx = blockIdx.x * 256 + threadIdx.x;
    if (idx < C2*CIN) {
        float v = w_in[idx];
        ushort h = f2bf(v);
        whi_in[idx] = h;
        wlo_in[idx] = f2bf(v - bf2f(h));
    }
    int j = idx - C2*CIN;
    if (j >= 0 && j < CIN*HID) {
        float v = w_out[j];
        ushort h = f2bf(v);
        whi_out[j] = h;
        wlo_out[j] = f2bf(v - bf2f(h));
    }
}

// ---------------------------------------------------------------------------
// A1: GEMM1 via MFMA 16x16x32 bf16.  z[c][px] = sum_k w_in[c][k] * x[k][px]
// z stored as packed channel-pair uints: z4[cp][px] = bf16(2cp) | bf16(2cp+1)<<16
// ---------------------------------------------------------------------------
__global__ __launch_bounds__(256)
void gemm1_mfma(const float* __restrict__ x,
                const ushort* __restrict__ whi, const ushort* __restrict__ wlo,
                uint* __restrict__ z4, int b0) {
    int t = threadIdx.x;
    int l = t & 63, wv = t >> 6;
    int lm = l & 15, g4 = l >> 4;
    int px0 = blockIdx.x * 64;
    int bg = blockIdx.y;
    const float* xb = x + (size_t)(b0 + bg) * CIN * NPX;
    uint* zb = z4 + (size_t)bg * HID * NPX;

    f32x4 acc[6][4];
#pragma unroll
    for (int mf = 0; mf < 6; ++mf)
#pragma unroll
        for (int nf = 0; nf < 4; ++nf) acc[mf][nf] = (f32x4){0.f,0.f,0.f,0.f};

#pragma unroll
    for (int kc = 0; kc < 3; ++kc) {
        int k0 = kc*32 + g4*8;
        bf16x8 bfr[4];
#pragma unroll
        for (int nf = 0; nf < 4; ++nf) {
            const float* xp = xb + (size_t)k0 * NPX + px0 + nf*16 + lm;
            bf16x8 v;
#pragma unroll
            for (int j = 0; j < 8; ++j) v[j] = (short)f2bf(xp[(size_t)j * NPX]);
            bfr[nf] = v;
        }
#pragma unroll
        for (int mf = 0; mf < 6; ++mf) {
            int row = wv*96 + mf*16 + lm;
            bf16x8 ah = *(const bf16x8*)(whi + (size_t)row*CIN + k0);
            bf16x8 al = *(const bf16x8*)(wlo + (size_t)row*CIN + k0);
#pragma unroll
            for (int nf = 0; nf < 4; ++nf) {
                acc[mf][nf] = __builtin_amdgcn_mfma_f32_16x16x32_bf16(ah, bfr[nf], acc[mf][nf], 0,0,0);
                acc[mf][nf] = __builtin_amdgcn_mfma_f32_16x16x32_bf16(al, bfr[nf], acc[mf][nf], 0,0,0);
            }
        }
    }
#pragma unroll
    for (int mf = 0; mf < 6; ++mf)
#pragma unroll
        for (int nf = 0; nf < 4; ++nf) {
            int px = px0 + nf*16 + lm;
            int basech = wv*96 + mf*16 + g4*4;
            int cp = basech >> 1;
            uint u01 = (uint)f2bf(acc[mf][nf][0]) | ((uint)f2bf(acc[mf][nf][1]) << 16);
            uint u23 = (uint)f2bf(acc[mf][nf][2]) | ((uint)f2bf(acc[mf][nf][3]) << 16);
            zb[(size_t)cp * NPX + px]       = u01;
            zb[(size_t)(cp+1) * NPX + px]   = u23;
        }
}

// ---------------------------------------------------------------------------
// A2: spectral-gate fixup on packed z. No-op when allflag (fft_w == ones).
// ---------------------------------------------------------------------------
__global__ __launch_bounds__(256)
void gate_fix(uint* __restrict__ z4, const float* __restrict__ g,
              const int* __restrict__ flags, const int* __restrict__ allflag) {
    if (allflag[0]) return;
    int pid = blockIdx.x;
    int bg = blockIdx.y;
    int ph = pid >> 5, pw = pid & 31;
    int t = threadIdx.x, l = t & 63, wv = t >> 6;
    int p1 = l >> 3, p2 = l & 7;
    uint* zb = z4 + (size_t)bg * HID * NPX;
    size_t base = (size_t)(ph*8) * W_ + pw*8;
    for (int cp = wv; cp < HID; cp += 4) {
        int f0 = flags[2*cp], f1 = flags[2*cp+1];
        if (f0 & f1) continue;
        const float* gc0 = g + (2*cp)*64;
        const float* gc1 = gc0 + 64;
        size_t zi = (size_t)cp * NPX + base + (size_t)p1 * W_ + p2;
        uint u = zb[zi];
        float v0 = extc(u, 0), v1 = extc(u, 1);
        float s0 = 0.f, s1 = 0.f;
        for (int q = 0; q < 64; ++q) {
            int idx = ((p1 - (q >> 3)) & 7)*8 + ((p2 - (q & 7)) & 7);
            s0 += __shfl(v0, q, 64) * gc0[idx];
            s1 += __shfl(v1, q, 64) * gc1[idx];
        }
        float r0 = f0 ? v0 : s0;
        float r1 = f1 ? v1 : s1;
        zb[zi] = (uint)f2bf(r0) | ((uint)f2bf(r1) << 16);
    }
}

// ---------------------------------------------------------------------------
// B1 v4: barrier-free streaming depthwise 3x3 + GELU gating, PLANAR output.
// Wave = 256-px row x 4-row strip x one packed plane-pair, rolling 3-row
// register pipeline, depth-1 row prefetch, shfl column halo. No LDS.
// Output: tg4[slice][px] planar packed pairs -> one uint4 store per row
// per thread (full-line coalesced; fixes 4x HBM write amplification).
// Grid: (16 strip-groups, 24 jg, nb); block = 256 = 4 waves = 4 strips.
// ---------------------------------------------------------------------------
constexpr int DROWS = 4;
__global__ __launch_bounds__(256)
void dw_gelu5(const uint* __restrict__ z4, const float* __restrict__ w_dw,
              uint* __restrict__ tg4) {
    int t = threadIdx.x;
    int wv = t >> 6, lane = t & 63;
    int strip = blockIdx.x * 4 + wv;       // 0..63
    int jg = blockIdx.y;                   // 0..23
    int bg = blockIdx.z;
    int row0 = strip * DROWS;
    int cb = lane * 4;
    const uint* zb = z4 + (size_t)bg * HID * NPX;
    uint* tb = tg4 + (size_t)bg * HID/2 * NPX;

#pragma unroll
    for (int pp = 0; pp < 4; ++pp) {
        int c  = jg*8 + pp*2;              // z1 channels c, c+1 (plane p1)
        int p1 = c >> 1;
        int p2 = p1 + 96;                  // z2 channels c+192, c+193
        // wave-uniform weights -> scalar regs
        float wA[18], wB[18];
#pragma unroll
        for (int k = 0; k < 18; ++k) {
            wA[k] = w_dw[(size_t)c*9 + k];
            wB[k] = w_dw[(size_t)(c+HID)*9 + k];
        }

        float accA[2][2][4], accB[2][2][4];   // [src][sub][px]
#pragma unroll
        for (int s = 0; s < 2; ++s)
#pragma unroll
            for (int u = 0; u < 2; ++u)
#pragma unroll
                for (int j = 0; j < 4; ++j) { accA[s][u][j]=0.f; accB[s][u][j]=0.f; }

        auto ld = [&](int r, uint4& A, uint4& B) {
            int y = row0 - 1 + r;
            A = (uint4){0,0,0,0}; B = (uint4){0,0,0,0};
            if (y >= 0 && y < H_) {
                A = *(const uint4*)(zb + (size_t)p1*NPX + (size_t)y*W_ + cb);
                B = *(const uint4*)(zb + (size_t)p2*NPX + (size_t)y*W_ + cb);
            }
        };

        uint4 a_cur, b_cur;
        ld(0, a_cur, b_cur);
#pragma unroll
        for (int r = 0; r < DROWS + 2; ++r) {
            uint4 a_nxt, b_nxt;
            if (r < DROWS + 1) ld(r + 1, a_nxt, b_nxt);

            uint aL = (uint)__shfl_up((int)a_cur.w, 1, 64);  if (lane == 0)  aL = 0u;
            uint aR = (uint)__shfl_down((int)a_cur.x, 1, 64); if (lane == 63) aR = 0u;
            uint bL = (uint)__shfl_up((int)b_cur.w, 1, 64);  if (lane == 0)  bL = 0u;
            uint bR = (uint)__shfl_down((int)b_cur.x, 1, 64); if (lane == 63) bR = 0u;

            float dA[2][4], dB[2][4];
#pragma unroll
            for (int sub = 0; sub < 2; ++sub) {
                {   // src A (z1)
                    float xv[6] = {extc(aL,sub), extc(a_cur.x,sub), extc(a_cur.y,sub),
                                   extc(a_cur.z,sub), extc(a_cur.w,sub), extc(aR,sub)};
                    const float* w = &wA[sub*9];
#pragma unroll
                    for (int j = 0; j < 4; ++j) {
                        float h2 = fmaf(xv[j],w[6], fmaf(xv[j+1],w[7], xv[j+2]*w[8]));
                        float h1 = fmaf(xv[j],w[3], fmaf(xv[j+1],w[4], xv[j+2]*w[5]));
                        float h0 = fmaf(xv[j],w[0], fmaf(xv[j+1],w[1], xv[j+2]*w[2]));
                        dA[sub][j]    = accA[0][sub][j] + h2;
                        accA[0][sub][j] = accB[0][sub][j] + h1;
                        accB[0][sub][j] = h0;
                    }
                }
                {   // src B (z2)
                    float xv[6] = {extc(bL,sub), extc(b_cur.x,sub), extc(b_cur.y,sub),
                                   extc(b_cur.z,sub), extc(b_cur.w,sub), extc(bR,sub)};
                    const float* w = &wB[sub*9];
#pragma unroll
                    for (int j = 0; j < 4; ++j) {
                        float h2 = fmaf(xv[j],w[6], fmaf(xv[j+1],w[7], xv[j+2]*w[8]));
                        float h1 = fmaf(xv[j],w[3], fmaf(xv[j+1],w[4], xv[j+2]*w[5]));
                        float h0 = fmaf(xv[j],w[0], fmaf(xv[j+1],w[1], xv[j+2]*w[2]));
                        dB[sub][j]    = accA[1][sub][j] + h2;
                        accA[1][sub][j] = accB[1][sub][j] + h1;
                        accB[1][sub][j] = h0;
                    }
                }
            }

            if (r >= 2) {
                int o = row0 + r - 2;
                uint4 val;
                val.x = (uint)f2bf(gelu_f(dA[0][0]) * dB[0][0]) |
                        (((uint)f2bf(gelu_f(dA[1][0]) * dB[1][0])) << 16);
                val.y = (uint)f2bf(gelu_f(dA[0][1]) * dB[0][1]) |
                        (((uint)f2bf(gelu_f(dA[1][1]) * dB[1][1])) << 16);
                val.z = (uint)f2bf(gelu_f(dA[0][2]) * dB[0][2]) |
                        (((uint)f2bf(gelu_f(dA[1][2]) * dB[1][2])) << 16);
                val.w = (uint)f2bf(gelu_f(dA[0][3]) * dB[0][3]) |
                        (((uint)f2bf(gelu_f(dA[1][3]) * dB[1][3])) << 16);
                *(uint4*)(tb + (size_t)(jg*4 + pp) * NPX + (size_t)o * W_ + cb) = val;
            }
            a_cur = a_nxt; b_cur = b_nxt;
        }
    }
}

// ---------------------------------------------------------------------------
// B2: GEMM2 via MFMA, all 96 oc per block; B-frags assembled from 4 planar
// b32 loads (slice q holds packed channels 2q,2q+1 -> frag word q).
// ---------------------------------------------------------------------------
__global__ __launch_bounds__(256)
void gemm2_mfma(const uint* __restrict__ tg4,
                const ushort* __restrict__ whi, const ushort* __restrict__ wlo,
                float* __restrict__ out, int b0) {
    int t = threadIdx.x;
    int l = t & 63, wv = t >> 6;
    int lm = l & 15, g4 = l >> 4;
    int h = blockIdx.x;
    int bg = blockIdx.z;
    int px0 = h * W_ + wv*64;
    const uint* tb = tg4 + (size_t)bg * HID/2 * NPX;

    f32x4 acc[6][4];
#pragma unroll
    for (int mf = 0; mf < 6; ++mf)
#pragma unroll
        for (int nf = 0; nf < 4; ++nf) acc[mf][nf] = (f32x4){0.f,0.f,0.f,0.f};

#pragma unroll
    for (int kc = 0; kc < 6; ++kc) {
        int s0 = kc*16 + g4*4;
        bf16x8 bfr[4];
#pragma unroll
        for (int nf = 0; nf < 4; ++nf) {
            int px = px0 + nf*16 + lm;
            uint4 u;
            u.x = tb[(size_t)(s0+0)*NPX + px];
            u.y = tb[(size_t)(s0+1)*NPX + px];
            u.z = tb[(size_t)(s0+2)*NPX + px];
            u.w = tb[(size_t)(s0+3)*NPX + px];
            bf16x8 v; __builtin_memcpy(&v, &u, 16);
            bfr[nf] = v;
        }
        int k0 = kc*32 + g4*8;
#pragma unroll
        for (int mf = 0; mf < 6; ++mf) {
            int row = mf*16 + lm;
            bf16x8 ah = *(const bf16x8*)(whi + (size_t)row*HID + k0);
            bf16x8 al = *(const bf16x8*)(wlo + (size_t)row*HID + k0);
#pragma unroll
            for (int nf = 0; nf < 4; ++nf) {
                acc[mf][nf] = __builtin_amdgcn_mfma_f32_16x16x32_bf16(ah, bfr[nf], acc[mf][nf], 0,0,0);
                acc[mf][nf] = __builtin_amdgcn_mfma_f32_16x16x32_bf16(al, bfr[nf], acc[mf][nf], 0,0,0);
            }
        }
    }
    float* ob = out + (size_t)(b0 + bg) * CIN * NPX;
#pragma unroll
    for (int mf = 0; mf < 6; ++mf)
#pragma unroll
        for (int nf = 0; nf < 4; ++nf)
#pragma unroll
            for (int r = 0; r < 4; ++r) {
                int oc = mf*16 + g4*4 + r;
                ob[(size_t)oc * NPX + px0 + nf*16 + lm] = acc[mf][nf][r];
            }
}

// ---------------------------------------------------------------------------
extern "C" void kernel_launch(void* const* d_in, const int* in_sizes, int n_in,
                              void* d_out, int out_size, void* d_ws, size_t ws_size,
                              hipStream_t stream) {
    const float* x     = (const float*)d_in[0];
    const float* w_in  = (const float*)d_in[1];
    const float* w_dw  = (const float*)d_in[2];
    const float* fftw  = (const float*)d_in[3];
    const float* w_out = (const float*)d_in[4];
    float* out = (float*)d_out;

    char* ws = (char*)d_ws;
    ushort* whi_in  = (ushort*)(ws + 0);        //  73728
    ushort* wlo_in  = (ushort*)(ws + 73728);    //  73728
    ushort* whi_out = (ushort*)(ws + 147456);   //  36864
    ushort* wlo_out = (ushort*)(ws + 184320);   //  36864
    float*  g       = (float*) (ws + 221184);   //  98304
    int*    flags   = (int*)   (ws + 319488);   //   1536
    int*    allflag = (int*)   (ws + 321024);   //      4

    const size_t zoff   = 327680;
    const size_t zbytes = (size_t)HID * NPX * 4;   // 50331648 per batch (packed)
    const size_t tbytes = (size_t)(HID/2) * NPX * 4; // 25165824 per batch (planar)
    size_t avail = (ws_size > zoff) ? ws_size - zoff : 0;
    int nbg = (int)(avail / (zbytes + tbytes));
    if (nbg < 1) nbg = 1;
    if (nbg > B_) nbg = B_;
    uint* z4  = (uint*)(ws + zoff);
    uint* tg4 = (uint*)(ws + zoff + (size_t)nbg * zbytes);

    prep_gate<<<dim3(C2), dim3(64), 0, stream>>>(fftw, g, flags);
    reduce_flags<<<dim3(1), dim3(64), 0, stream>>>(flags, allflag);
    prep_w<<<dim3(216), dim3(256), 0, stream>>>(w_in, w_out,
                                                whi_in, wlo_in, whi_out, wlo_out);

    for (int b0 = 0; b0 < B_; b0 += nbg) {
        int nb = (B_ - b0 < nbg) ? (B_ - b0) : nbg;
        gemm1_mfma<<<dim3(NPX/64, nb), dim3(256), 0, stream>>>(x, whi_in, wlo_in, z4, b0);
        gate_fix<<<dim3(HP*WP, nb), dim3(256), 0, stream>>>(z4, g, flags, allflag);
        dw_gelu5<<<dim3(H_/DROWS/4, 24, nb), dim3(256), 0, stream>>>(z4, w_dw, tg4);
        gemm2_mfma<<<dim3(H_, 1, nb), dim3(256), 0, stream>>>(tg4, whi_out, wlo_out, out, b0);
    }
}

// Round 7
// 242.584 us; speedup vs baseline: 1.6285x; 1.0293x over previous
//
#include <hip/hip_runtime.h>
#include <hip/hip_bf16.h>
#include <math.h>

typedef short bf16x8 __attribute__((ext_vector_type(8)));
typedef float f32x4  __attribute__((ext_vector_type(4)));

constexpr int B_=4, CIN=96, H_=256, W_=256, HID=192, C2=384;
constexpr int NPX = H_*W_;          // 65536 px per plane
#define PB 8
constexpr int HP = H_/PB, WP = W_/PB;

__device__ __forceinline__ ushort f2bf(float f) {
    __hip_bfloat16 h = __float2bfloat16(f);
    ushort u; __builtin_memcpy(&u, &h, 2); return u;
}
__device__ __forceinline__ float bf2f(ushort u) {
    __hip_bfloat16 h; __builtin_memcpy(&h, &u, 2); return __bfloat162float(h);
}
// extract channel sub (0=lo,1=hi) of a packed bf16-pair uint as float
__device__ __forceinline__ float extc(uint u, int sub) {
    uint w = sub ? (u & 0xffff0000u) : (u << 16);
    float f; __builtin_memcpy(&f, &w, 4); return f;
}

// Fast exact-erf GELU: A&S 7.1.26 rational approx, |err| <= ~2e-7 abs.
__device__ __forceinline__ float gelu_f(float x) {
    float u  = x * 0.70710678118654752f;
    float au = fabsf(u);
    float t  = __builtin_amdgcn_rcpf(fmaf(0.3275911f, au, 1.0f));
    float poly = t * fmaf(t, fmaf(t, fmaf(t, fmaf(t, 1.061405429f,
                     -1.453152027f), 1.421413741f), -0.284496736f),
                     0.254829592f);
    float e  = __builtin_amdgcn_exp2f(au * au * -1.4426950408889634f);
    float g  = fmaf(-poly, e, 1.0f);          // erf(|u|)
    float one_plus = 1.0f + copysignf(g, u);  // 1 + erf(u)
    return 0.5f * x * one_plus;
}

// ---------------------------------------------------------------------------
// prep_gate: per-channel 8x8 spatial gate kernel from fft_w (+identity flags).
// ---------------------------------------------------------------------------
__global__ void prep_gate(const float* __restrict__ fftw,
                          float* __restrict__ g, int* __restrict__ flags) {
    int c = blockIdx.x;
    int t = threadIdx.x;             // one wave
    int n1 = t >> 3, n2 = t & 7;
    const float* Wc = fftw + c * 40;
    const double ct[8] = {1.0, 0.70710678118654752, 0.0, -0.70710678118654752,
                          -1.0, -0.70710678118654752, 0.0, 0.70710678118654752};
    double acc = 0.0;
    for (int k1 = 0; k1 < 8; ++k1)
        for (int k2 = 0; k2 < 8; ++k2) {
            double geff;
            if (k2 == 0 || k2 == 4)
                geff = 0.5 * ((double)Wc[k1*5+k2] + (double)Wc[((8-k1)&7)*5+k2]);
            else if (k2 < 4) geff = (double)Wc[k1*5+k2];
            else             geff = (double)Wc[((8-k1)&7)*5 + (8-k2)];
            acc += geff * ct[(k1*n1 + k2*n2) & 7];
        }
    acc *= (1.0/64.0);
    g[c*64 + t] = (float)acc;
    double expect = (t == 0) ? 1.0 : 0.0;
    unsigned long long m = __ballot(fabs(acc - expect) <= 1e-6);
    if (t == 0) flags[c] = (m == 0xFFFFFFFFFFFFFFFFull) ? 1 : 0;
}

__global__ void reduce_flags(const int* __restrict__ flags,
                             int* __restrict__ allflag) {
    int t = threadIdx.x;             // 64
    int ok = 1;
    for (int j = t; j < C2; j += 64) ok &= flags[j];
    unsigned long long m = __ballot(ok != 0);
    if (t == 0) allflag[0] = (m == 0xFFFFFFFFFFFFFFFFull) ? 1 : 0;
}

// ---------------------------------------------------------------------------
// prep_w: split weights into bf16 hi + lo (residual) pairs.
// ---------------------------------------------------------------------------
__global__ void prep_w(const float* __restrict__ w_in, const float* __restrict__ w_out,
                       ushort* __restrict__ whi_in,  ushort* __restrict__ wlo_in,
                       ushort* __restrict__ whi_out, ushort* __restrict__ wlo_out) {
    int idx = blockIdx.x * 256 + threadIdx.x;
    if (idx < C2*CIN) {
        float v = w_in[idx];
        ushort h = f2bf(v);
        whi_in[idx] = h;
        wlo_in[idx] = f2bf(v - bf2f(h));
    }
    int j = idx - C2*CIN;
    if (j >= 0 && j < CIN*HID) {
        float v = w_out[j];
        ushort h = f2bf(v);
        whi_out[j] = h;
        wlo_out[j] = f2bf(v - bf2f(h));
    }
}

// ---------------------------------------------------------------------------
// A1 v2: GEMM1 via MFMA, LDS-staged x.
// Block: 512 thr / 8 waves, 64 px; wave owns 48 oc (acc = 48 regs).
// x[96ch][64px] fp32 staged once -> LDS bf16 [64px][104ch] (pad -> ~2-way
// bank conflicts on ds_read_b128); single barrier; B-frags = ds_read_b128.
// z stored as packed channel-pair uints (planar).
// ---------------------------------------------------------------------------
__global__ __launch_bounds__(512)
void gemm1_mfma(const float* __restrict__ x,
                const ushort* __restrict__ whi, const ushort* __restrict__ wlo,
                uint* __restrict__ z4, int b0) {
    __shared__ ushort xs[64][104];
    int t = threadIdx.x;
    int l = t & 63, wv = t >> 6;          // 8 waves
    int lm = l & 15, g4 = l >> 4;
    int px0 = blockIdx.x * 64;
    int bg = blockIdx.y;
    const float* xb = x + (size_t)(b0 + bg) * CIN * NPX;
    uint* zb = z4 + (size_t)bg * HID * NPX;

    // stage x -> LDS bf16, transposed to [px][ch]
#pragma unroll
    for (int i = 0; i < 3; ++i) {
        int fi = t + i * 512;             // 0..1535 over [96ch][16 float4]
        int ch = fi >> 4, c4 = fi & 15;
        float4 v = *(const float4*)(xb + (size_t)ch * NPX + px0 + c4 * 4);
        xs[c4*4+0][ch] = f2bf(v.x);
        xs[c4*4+1][ch] = f2bf(v.y);
        xs[c4*4+2][ch] = f2bf(v.z);
        xs[c4*4+3][ch] = f2bf(v.w);
    }
    __syncthreads();

    f32x4 acc[3][4];
#pragma unroll
    for (int mf = 0; mf < 3; ++mf)
#pragma unroll
        for (int nf = 0; nf < 4; ++nf) acc[mf][nf] = (f32x4){0.f,0.f,0.f,0.f};

#pragma unroll
    for (int kc = 0; kc < 3; ++kc) {
        int k0 = kc*32 + g4*8;
        bf16x8 bfr[4];
#pragma unroll
        for (int nf = 0; nf < 4; ++nf)
            bfr[nf] = *(const bf16x8*)&xs[nf*16 + lm][k0];
#pragma unroll
        for (int mf = 0; mf < 3; ++mf) {
            int row = wv*48 + mf*16 + lm;
            bf16x8 ah = *(const bf16x8*)(whi + (size_t)row*CIN + k0);
            bf16x8 al = *(const bf16x8*)(wlo + (size_t)row*CIN + k0);
#pragma unroll
            for (int nf = 0; nf < 4; ++nf) {
                acc[mf][nf] = __builtin_amdgcn_mfma_f32_16x16x32_bf16(ah, bfr[nf], acc[mf][nf], 0,0,0);
                acc[mf][nf] = __builtin_amdgcn_mfma_f32_16x16x32_bf16(al, bfr[nf], acc[mf][nf], 0,0,0);
            }
        }
    }
    // C/D: col = lane&15 (px), row = g4*4 + r (channel) -> pack pairs
#pragma unroll
    for (int mf = 0; mf < 3; ++mf)
#pragma unroll
        for (int nf = 0; nf < 4; ++nf) {
            int px = px0 + nf*16 + lm;
            int basech = wv*48 + mf*16 + g4*4;
            int cp = basech >> 1;
            uint u01 = (uint)f2bf(acc[mf][nf][0]) | ((uint)f2bf(acc[mf][nf][1]) << 16);
            uint u23 = (uint)f2bf(acc[mf][nf][2]) | ((uint)f2bf(acc[mf][nf][3]) << 16);
            zb[(size_t)cp * NPX + px]     = u01;
            zb[(size_t)(cp+1) * NPX + px] = u23;
        }
}

// ---------------------------------------------------------------------------
// A2: spectral-gate fixup on packed z. No-op when allflag (fft_w == ones).
// ---------------------------------------------------------------------------
__global__ __launch_bounds__(256)
void gate_fix(uint* __restrict__ z4, const float* __restrict__ g,
              const int* __restrict__ flags, const int* __restrict__ allflag) {
    if (allflag[0]) return;
    int pid = blockIdx.x;
    int bg = blockIdx.y;
    int ph = pid >> 5, pw = pid & 31;
    int t = threadIdx.x, l = t & 63, wv = t >> 6;
    int p1 = l >> 3, p2 = l & 7;
    uint* zb = z4 + (size_t)bg * HID * NPX;
    size_t base = (size_t)(ph*8) * W_ + pw*8;
    for (int cp = wv; cp < HID; cp += 4) {
        int f0 = flags[2*cp], f1 = flags[2*cp+1];
        if (f0 & f1) continue;
        const float* gc0 = g + (2*cp)*64;
        const float* gc1 = gc0 + 64;
        size_t zi = (size_t)cp * NPX + base + (size_t)p1 * W_ + p2;
        uint u = zb[zi];
        float v0 = extc(u, 0), v1 = extc(u, 1);
        float s0 = 0.f, s1 = 0.f;
        for (int q = 0; q < 64; ++q) {
            int idx = ((p1 - (q >> 3)) & 7)*8 + ((p2 - (q & 7)) & 7);
            s0 += __shfl(v0, q, 64) * gc0[idx];
            s1 += __shfl(v1, q, 64) * gc1[idx];
        }
        float r0 = f0 ? v0 : s0;
        float r1 = f1 ? v1 : s1;
        zb[zi] = (uint)f2bf(r0) | ((uint)f2bf(r1) << 16);
    }
}

// ---------------------------------------------------------------------------
// B1: barrier-free streaming depthwise 3x3 + GELU gating, PLANAR output.
// Wave = 256-px row x 8-row strip x one packed plane-pair, rolling 3-row
// register pipeline, depth-1 row prefetch, shfl column halo. No LDS.
// Grid: (8 strip-groups, 24 jg, nb); block = 256 = 4 waves = 4 strips.
// ---------------------------------------------------------------------------
constexpr int DROWS = 8;
__global__ __launch_bounds__(256)
void dw_gelu5(const uint* __restrict__ z4, const float* __restrict__ w_dw,
              uint* __restrict__ tg4) {
    int t = threadIdx.x;
    int wv = t >> 6, lane = t & 63;
    int strip = blockIdx.x * 4 + wv;       // 0..31
    int jg = blockIdx.y;                   // 0..23
    int bg = blockIdx.z;
    int row0 = strip * DROWS;
    int cb = lane * 4;
    const uint* zb = z4 + (size_t)bg * HID * NPX;
    uint* tb = tg4 + (size_t)bg * HID/2 * NPX;

#pragma unroll
    for (int pp = 0; pp < 4; ++pp) {
        int c  = jg*8 + pp*2;              // z1 channels c, c+1 (plane p1)
        int p1 = c >> 1;
        int p2 = p1 + 96;                  // z2 channels c+192, c+193
        float wA[18], wB[18];
#pragma unroll
        for (int k = 0; k < 18; ++k) {
            wA[k] = w_dw[(size_t)c*9 + k];
            wB[k] = w_dw[(size_t)(c+HID)*9 + k];
        }

        float accA[2][2][4], accB[2][2][4];   // [src][sub][px]
#pragma unroll
        for (int s = 0; s < 2; ++s)
#pragma unroll
            for (int u = 0; u < 2; ++u)
#pragma unroll
                for (int j = 0; j < 4; ++j) { accA[s][u][j]=0.f; accB[s][u][j]=0.f; }

        auto ld = [&](int r, uint4& A, uint4& B) {
            int y = row0 - 1 + r;
            A = (uint4){0,0,0,0}; B = (uint4){0,0,0,0};
            if (y >= 0 && y < H_) {
                A = *(const uint4*)(zb + (size_t)p1*NPX + (size_t)y*W_ + cb);
                B = *(const uint4*)(zb + (size_t)p2*NPX + (size_t)y*W_ + cb);
            }
        };

        uint4 a_cur, b_cur;
        ld(0, a_cur, b_cur);
#pragma unroll
        for (int r = 0; r < DROWS + 2; ++r) {
            uint4 a_nxt, b_nxt;
            if (r < DROWS + 1) ld(r + 1, a_nxt, b_nxt);

            uint aL = (uint)__shfl_up((int)a_cur.w, 1, 64);  if (lane == 0)  aL = 0u;
            uint aR = (uint)__shfl_down((int)a_cur.x, 1, 64); if (lane == 63) aR = 0u;
            uint bL = (uint)__shfl_up((int)b_cur.w, 1, 64);  if (lane == 0)  bL = 0u;
            uint bR = (uint)__shfl_down((int)b_cur.x, 1, 64); if (lane == 63) bR = 0u;

            float dA[2][4], dB[2][4];
#pragma unroll
            for (int sub = 0; sub < 2; ++sub) {
                {   // src A (z1)
                    float xv[6] = {extc(aL,sub), extc(a_cur.x,sub), extc(a_cur.y,sub),
                                   extc(a_cur.z,sub), extc(a_cur.w,sub), extc(aR,sub)};
                    const float* w = &wA[sub*9];
#pragma unroll
                    for (int j = 0; j < 4; ++j) {
                        float h2 = fmaf(xv[j],w[6], fmaf(xv[j+1],w[7], xv[j+2]*w[8]));
                        float h1 = fmaf(xv[j],w[3], fmaf(xv[j+1],w[4], xv[j+2]*w[5]));
                        float h0 = fmaf(xv[j],w[0], fmaf(xv[j+1],w[1], xv[j+2]*w[2]));
                        dA[sub][j]    = accA[0][sub][j] + h2;
                        accA[0][sub][j] = accB[0][sub][j] + h1;
                        accB[0][sub][j] = h0;
                    }
                }
                {   // src B (z2)
                    float xv[6] = {extc(bL,sub), extc(b_cur.x,sub), extc(b_cur.y,sub),
                                   extc(b_cur.z,sub), extc(b_cur.w,sub), extc(bR,sub)};
                    const float* w = &wB[sub*9];
#pragma unroll
                    for (int j = 0; j < 4; ++j) {
                        float h2 = fmaf(xv[j],w[6], fmaf(xv[j+1],w[7], xv[j+2]*w[8]));
                        float h1 = fmaf(xv[j],w[3], fmaf(xv[j+1],w[4], xv[j+2]*w[5]));
                        float h0 = fmaf(xv[j],w[0], fmaf(xv[j+1],w[1], xv[j+2]*w[2]));
                        dB[sub][j]    = accA[1][sub][j] + h2;
                        accA[1][sub][j] = accB[1][sub][j] + h1;
                        accB[1][sub][j] = h0;
                    }
                }
            }

            if (r >= 2) {
                int o = row0 + r - 2;
                uint4 val;
                val.x = (uint)f2bf(gelu_f(dA[0][0]) * dB[0][0]) |
                        (((uint)f2bf(gelu_f(dA[1][0]) * dB[1][0])) << 16);
                val.y = (uint)f2bf(gelu_f(dA[0][1]) * dB[0][1]) |
                        (((uint)f2bf(gelu_f(dA[1][1]) * dB[1][1])) << 16);
                val.z = (uint)f2bf(gelu_f(dA[0][2]) * dB[0][2]) |
                        (((uint)f2bf(gelu_f(dA[1][2]) * dB[1][2])) << 16);
                val.w = (uint)f2bf(gelu_f(dA[0][3]) * dB[0][3]) |
                        (((uint)f2bf(gelu_f(dA[1][3]) * dB[1][3])) << 16);
                *(uint4*)(tb + (size_t)(jg*4 + pp) * NPX + (size_t)o * W_ + cb) = val;
            }
            a_cur = a_nxt; b_cur = b_nxt;
        }
    }
}

// ---------------------------------------------------------------------------
// B2 v2: GEMM2 via MFMA, 8 waves: wave = 48 oc x 64 px; tg read from planar
// packed slices (slice q -> frag word q).
// Grid: (256 rows, 1, nb); block = 512.
// ---------------------------------------------------------------------------
__global__ __launch_bounds__(512)
void gemm2_mfma(const uint* __restrict__ tg4,
                const ushort* __restrict__ whi, const ushort* __restrict__ wlo,
                float* __restrict__ out, int b0) {
    int t = threadIdx.x;
    int l = t & 63, wv = t >> 6;          // 8 waves
    int ocg = wv & 1, pxg = wv >> 1;      // 2 oc halves x 4 px groups
    int lm = l & 15, g4 = l >> 4;
    int h = blockIdx.x;
    int bg = blockIdx.z;
    int px0 = h * W_ + pxg*64;
    const uint* tb = tg4 + (size_t)bg * HID/2 * NPX;

    f32x4 acc[3][4];
#pragma unroll
    for (int mf = 0; mf < 3; ++mf)
#pragma unroll
        for (int nf = 0; nf < 4; ++nf) acc[mf][nf] = (f32x4){0.f,0.f,0.f,0.f};

#pragma unroll
    for (int kc = 0; kc < 6; ++kc) {
        int s0 = kc*16 + g4*4;
        bf16x8 bfr[4];
#pragma unroll
        for (int nf = 0; nf < 4; ++nf) {
            int px = px0 + nf*16 + lm;
            uint4 u;
            u.x = tb[(size_t)(s0+0)*NPX + px];
            u.y = tb[(size_t)(s0+1)*NPX + px];
            u.z = tb[(size_t)(s0+2)*NPX + px];
            u.w = tb[(size_t)(s0+3)*NPX + px];
            bf16x8 v; __builtin_memcpy(&v, &u, 16);
            bfr[nf] = v;
        }
        int k0 = kc*32 + g4*8;
#pragma unroll
        for (int mf = 0; mf < 3; ++mf) {
            int row = ocg*48 + mf*16 + lm;
            bf16x8 ah = *(const bf16x8*)(whi + (size_t)row*HID + k0);
            bf16x8 al = *(const bf16x8*)(wlo + (size_t)row*HID + k0);
#pragma unroll
            for (int nf = 0; nf < 4; ++nf) {
                acc[mf][nf] = __builtin_amdgcn_mfma_f32_16x16x32_bf16(ah, bfr[nf], acc[mf][nf], 0,0,0);
                acc[mf][nf] = __builtin_amdgcn_mfma_f32_16x16x32_bf16(al, bfr[nf], acc[mf][nf], 0,0,0);
            }
        }
    }
    float* ob = out + (size_t)(b0 + bg) * CIN * NPX;
#pragma unroll
    for (int mf = 0; mf < 3; ++mf)
#pragma unroll
        for (int nf = 0; nf < 4; ++nf)
#pragma unroll
            for (int r = 0; r < 4; ++r) {
                int oc = ocg*48 + mf*16 + g4*4 + r;
                ob[(size_t)oc * NPX + px0 + nf*16 + lm] = acc[mf][nf][r];
            }
}

// ---------------------------------------------------------------------------
extern "C" void kernel_launch(void* const* d_in, const int* in_sizes, int n_in,
                              void* d_out, int out_size, void* d_ws, size_t ws_size,
                              hipStream_t stream) {
    const float* x     = (const float*)d_in[0];
    const float* w_in  = (const float*)d_in[1];
    const float* w_dw  = (const float*)d_in[2];
    const float* fftw  = (const float*)d_in[3];
    const float* w_out = (const float*)d_in[4];
    float* out = (float*)d_out;

    char* ws = (char*)d_ws;
    ushort* whi_in  = (ushort*)(ws + 0);        //  73728
    ushort* wlo_in  = (ushort*)(ws + 73728);    //  73728
    ushort* whi_out = (ushort*)(ws + 147456);   //  36864
    ushort* wlo_out = (ushort*)(ws + 184320);   //  36864
    float*  g       = (float*) (ws + 221184);   //  98304
    int*    flags   = (int*)   (ws + 319488);   //   1536
    int*    allflag = (int*)   (ws + 321024);   //      4

    const size_t zoff   = 327680;
    const size_t zbytes = (size_t)HID * NPX * 4;     // 50331648 per batch (packed)
    const size_t tbytes = (size_t)(HID/2) * NPX * 4; // 25165824 per batch (planar)
    size_t avail = (ws_size > zoff) ? ws_size - zoff : 0;
    int nbg = (int)(avail / (zbytes + tbytes));
    if (nbg < 1) nbg = 1;
    if (nbg > B_) nbg = B_;
    uint* z4  = (uint*)(ws + zoff);
    uint* tg4 = (uint*)(ws + zoff + (size_t)nbg * zbytes);

    prep_gate<<<dim3(C2), dim3(64), 0, stream>>>(fftw, g, flags);
    reduce_flags<<<dim3(1), dim3(64), 0, stream>>>(flags, allflag);
    prep_w<<<dim3(216), dim3(256), 0, stream>>>(w_in, w_out,
                                                whi_in, wlo_in, whi_out, wlo_out);

    for (int b0 = 0; b0 < B_; b0 += nbg) {
        int nb = (B_ - b0 < nbg) ? (B_ - b0) : nbg;
        gemm1_mfma<<<dim3(NPX/64, nb), dim3(512), 0, stream>>>(x, whi_in, wlo_in, z4, b0);
        gate_fix<<<dim3(HP*WP, nb), dim3(256), 0, stream>>>(z4, g, flags, allflag);
        dw_gelu5<<<dim3(H_/DROWS/4, 24, nb), dim3(256), 0, stream>>>(z4, w_dw, tg4);
        gemm2_mfma<<<dim3(H_, 1, nb), dim3(512), 0, stream>>>(tg4, whi_out, wlo_out, out, b0);
    }
}

// Round 8
// 240.569 us; speedup vs baseline: 1.6421x; 1.0084x over previous
//
#include <hip/hip_runtime.h>
#include <hip/hip_bf16.h>
#include <math.h>

typedef short bf16x8 __attribute__((ext_vector_type(8)));
typedef float f32x4  __attribute__((ext_vector_type(4)));

constexpr int B_=4, CIN=96, H_=256, W_=256, HID=192, C2=384;
constexpr int NPX = H_*W_;          // 65536 px per plane
#define PB 8
constexpr int HP = H_/PB, WP = W_/PB;

__device__ __forceinline__ ushort f2bf(float f) {
    __hip_bfloat16 h = __float2bfloat16(f);
    ushort u; __builtin_memcpy(&u, &h, 2); return u;
}
__device__ __forceinline__ float bf2f(ushort u) {
    __hip_bfloat16 h; __builtin_memcpy(&h, &u, 2); return __bfloat162float(h);
}
// extract channel sub (0=lo,1=hi) of a packed bf16-pair uint as float
__device__ __forceinline__ float extc(uint u, int sub) {
    uint w = sub ? (u & 0xffff0000u) : (u << 16);
    float f; __builtin_memcpy(&f, &w, 4); return f;
}

// Fast exact-erf GELU: A&S 7.1.26 rational approx, |err| <= ~2e-7 abs.
__device__ __forceinline__ float gelu_f(float x) {
    float u  = x * 0.70710678118654752f;
    float au = fabsf(u);
    float t  = __builtin_amdgcn_rcpf(fmaf(0.3275911f, au, 1.0f));
    float poly = t * fmaf(t, fmaf(t, fmaf(t, fmaf(t, 1.061405429f,
                     -1.453152027f), 1.421413741f), -0.284496736f),
                     0.254829592f);
    float e  = __builtin_amdgcn_exp2f(au * au * -1.4426950408889634f);
    float g  = fmaf(-poly, e, 1.0f);          // erf(|u|)
    float one_plus = 1.0f + copysignf(g, u);  // 1 + erf(u)
    return 0.5f * x * one_plus;
}

// ---------------------------------------------------------------------------
// prep_gate: per-channel 8x8 spatial gate kernel from fft_w (+identity flags).
// ---------------------------------------------------------------------------
__global__ void prep_gate(const float* __restrict__ fftw,
                          float* __restrict__ g, int* __restrict__ flags) {
    int c = blockIdx.x;
    int t = threadIdx.x;             // one wave
    int n1 = t >> 3, n2 = t & 7;
    const float* Wc = fftw + c * 40;
    const double ct[8] = {1.0, 0.70710678118654752, 0.0, -0.70710678118654752,
                          -1.0, -0.70710678118654752, 0.0, 0.70710678118654752};
    double acc = 0.0;
    for (int k1 = 0; k1 < 8; ++k1)
        for (int k2 = 0; k2 < 8; ++k2) {
            double geff;
            if (k2 == 0 || k2 == 4)
                geff = 0.5 * ((double)Wc[k1*5+k2] + (double)Wc[((8-k1)&7)*5+k2]);
            else if (k2 < 4) geff = (double)Wc[k1*5+k2];
            else             geff = (double)Wc[((8-k1)&7)*5 + (8-k2)];
            acc += geff * ct[(k1*n1 + k2*n2) & 7];
        }
    acc *= (1.0/64.0);
    g[c*64 + t] = (float)acc;
    double expect = (t == 0) ? 1.0 : 0.0;
    unsigned long long m = __ballot(fabs(acc - expect) <= 1e-6);
    if (t == 0) flags[c] = (m == 0xFFFFFFFFFFFFFFFFull) ? 1 : 0;
}

__global__ void reduce_flags(const int* __restrict__ flags,
                             int* __restrict__ allflag) {
    int t = threadIdx.x;             // 64
    int ok = 1;
    for (int j = t; j < C2; j += 64) ok &= flags[j];
    unsigned long long m = __ballot(ok != 0);
    if (t == 0) allflag[0] = (m == 0xFFFFFFFFFFFFFFFFull) ? 1 : 0;
}

// ---------------------------------------------------------------------------
// prep_w: split weights into bf16 hi + lo (residual) pairs.
// ---------------------------------------------------------------------------
__global__ void prep_w(const float* __restrict__ w_in, const float* __restrict__ w_out,
                       ushort* __restrict__ whi_in,  ushort* __restrict__ wlo_in,
                       ushort* __restrict__ whi_out, ushort* __restrict__ wlo_out) {
    int idx = blockIdx.x * 256 + threadIdx.x;
    if (idx < C2*CIN) {
        float v = w_in[idx];
        ushort h = f2bf(v);
        whi_in[idx] = h;
        wlo_in[idx] = f2bf(v - bf2f(h));
    }
    int j = idx - C2*CIN;
    if (j >= 0 && j < CIN*HID) {
        float v = w_out[j];
        ushort h = f2bf(v);
        whi_out[j] = h;
        wlo_out[j] = f2bf(v - bf2f(h));
    }
}

// ---------------------------------------------------------------------------
// A1 v3: GEMM1 via MFMA, conflict-free LDS staging.
// Block: 512 thr / 8 waves, 64 px; wave owns 48 oc (acc = 48 regs).
// Staging: item (cp,q) loads x[2cp] & x[2cp+1] float4 (4 px), packs into
// 4 uints, writes lds[px][cp] — lanes hit consecutive LDS dwords (<=2-way).
// Fragment read: one ds_read_b128 of 4 packed uints at row px (row pitch
// 208 B -> 20*px%32 start-bank pattern tiles all 32 banks: conflict-free).
// ---------------------------------------------------------------------------
__global__ __launch_bounds__(512)
void gemm1_mfma(const float* __restrict__ x,
                const ushort* __restrict__ whi, const ushort* __restrict__ wlo,
                uint* __restrict__ z4, int b0) {
    __shared__ uint xs[64][52];           // [px][48 cp + 4 pad]
    int t = threadIdx.x;
    int l = t & 63, wv = t >> 6;          // 8 waves
    int lm = l & 15, g4 = l >> 4;
    int px0 = blockIdx.x * 64;
    int bg = blockIdx.y;
    const float* xb = x + (size_t)(b0 + bg) * CIN * NPX;
    uint* zb = z4 + (size_t)bg * HID * NPX;

    // stage x -> LDS packed channel pairs [px][cp]
#pragma unroll
    for (int i = 0; i < 2; ++i) {
        int item = t + i * 512;           // [q][cp] order: cp fastest
        if (item < 768) {
            int q  = item / 48;           // 0..15 (px quad)
            int cp = item - q * 48;       // 0..47 (channel pair)
            const float* pa = xb + (size_t)(2*cp) * NPX + px0 + 4*q;
            float4 a = *(const float4*)pa;
            float4 b = *(const float4*)(pa + NPX);
            xs[4*q+0][cp] = (uint)f2bf(a.x) | ((uint)f2bf(b.x) << 16);
            xs[4*q+1][cp] = (uint)f2bf(a.y) | ((uint)f2bf(b.y) << 16);
            xs[4*q+2][cp] = (uint)f2bf(a.z) | ((uint)f2bf(b.z) << 16);
            xs[4*q+3][cp] = (uint)f2bf(a.w) | ((uint)f2bf(b.w) << 16);
        }
    }
    __syncthreads();

    f32x4 acc[3][4];
#pragma unroll
    for (int mf = 0; mf < 3; ++mf)
#pragma unroll
        for (int nf = 0; nf < 4; ++nf) acc[mf][nf] = (f32x4){0.f,0.f,0.f,0.f};

#pragma unroll
    for (int kc = 0; kc < 3; ++kc) {
        int k0  = kc*32 + g4*8;
        int cp0 = kc*16 + g4*4;
        bf16x8 bfr[4];
#pragma unroll
        for (int nf = 0; nf < 4; ++nf)
            bfr[nf] = *(const bf16x8*)&xs[nf*16 + lm][cp0];
#pragma unroll
        for (int mf = 0; mf < 3; ++mf) {
            int row = wv*48 + mf*16 + lm;
            bf16x8 ah = *(const bf16x8*)(whi + (size_t)row*CIN + k0);
            bf16x8 al = *(const bf16x8*)(wlo + (size_t)row*CIN + k0);
#pragma unroll
            for (int nf = 0; nf < 4; ++nf) {
                acc[mf][nf] = __builtin_amdgcn_mfma_f32_16x16x32_bf16(ah, bfr[nf], acc[mf][nf], 0,0,0);
                acc[mf][nf] = __builtin_amdgcn_mfma_f32_16x16x32_bf16(al, bfr[nf], acc[mf][nf], 0,0,0);
            }
        }
    }
    // C/D: col = lane&15 (px), row = g4*4 + r (channel) -> pack pairs
#pragma unroll
    for (int mf = 0; mf < 3; ++mf)
#pragma unroll
        for (int nf = 0; nf < 4; ++nf) {
            int px = px0 + nf*16 + lm;
            int basech = wv*48 + mf*16 + g4*4;
            int cp = basech >> 1;
            uint u01 = (uint)f2bf(acc[mf][nf][0]) | ((uint)f2bf(acc[mf][nf][1]) << 16);
            uint u23 = (uint)f2bf(acc[mf][nf][2]) | ((uint)f2bf(acc[mf][nf][3]) << 16);
            zb[(size_t)cp * NPX + px]     = u01;
            zb[(size_t)(cp+1) * NPX + px] = u23;
        }
}

// ---------------------------------------------------------------------------
// A2: spectral-gate fixup on packed z. No-op when allflag (fft_w == ones).
// ---------------------------------------------------------------------------
__global__ __launch_bounds__(256)
void gate_fix(uint* __restrict__ z4, const float* __restrict__ g,
              const int* __restrict__ flags, const int* __restrict__ allflag) {
    if (allflag[0]) return;
    int pid = blockIdx.x;
    int bg = blockIdx.y;
    int ph = pid >> 5, pw = pid & 31;
    int t = threadIdx.x, l = t & 63, wv = t >> 6;
    int p1 = l >> 3, p2 = l & 7;
    uint* zb = z4 + (size_t)bg * HID * NPX;
    size_t base = (size_t)(ph*8) * W_ + pw*8;
    for (int cp = wv; cp < HID; cp += 4) {
        int f0 = flags[2*cp], f1 = flags[2*cp+1];
        if (f0 & f1) continue;
        const float* gc0 = g + (2*cp)*64;
        const float* gc1 = gc0 + 64;
        size_t zi = (size_t)cp * NPX + base + (size_t)p1 * W_ + p2;
        uint u = zb[zi];
        float v0 = extc(u, 0), v1 = extc(u, 1);
        float s0 = 0.f, s1 = 0.f;
        for (int q = 0; q < 64; ++q) {
            int idx = ((p1 - (q >> 3)) & 7)*8 + ((p2 - (q & 7)) & 7);
            s0 += __shfl(v0, q, 64) * gc0[idx];
            s1 += __shfl(v1, q, 64) * gc1[idx];
        }
        float r0 = f0 ? v0 : s0;
        float r1 = f1 ? v1 : s1;
        zb[zi] = (uint)f2bf(r0) | ((uint)f2bf(r1) << 16);
    }
}

// ---------------------------------------------------------------------------
// B1 v5: barrier-free streaming depthwise 3x3 + GELU gating, PLANAR output.
// Wave = 256-px row x 8-row strip x one packed plane-pair; pp moved to grid
// (4x blocks vs v4 for TLP). Rolling 3-row register pipeline, depth-1 row
// prefetch, shfl column halo. No LDS.
// Grid: (8 strip-groups, 96 [jg*4+pp], nb); block = 256 = 4 waves = 4 strips.
// ---------------------------------------------------------------------------
constexpr int DROWS = 8;
__global__ __launch_bounds__(256)
void dw_gelu6(const uint* __restrict__ z4, const float* __restrict__ w_dw,
              uint* __restrict__ tg4) {
    int t = threadIdx.x;
    int wv = t >> 6, lane = t & 63;
    int strip = blockIdx.x * 4 + wv;       // 0..31
    int s = blockIdx.y;                    // 0..95: jg = s>>2, pp = s&3
    int jg = s >> 2, pp = s & 3;
    int bg = blockIdx.z;
    int row0 = strip * DROWS;
    int cb = lane * 4;
    const uint* zb = z4 + (size_t)bg * HID * NPX;
    uint* tb = tg4 + (size_t)bg * HID/2 * NPX;

    int c  = jg*8 + pp*2;                  // z1 channels c, c+1 (plane p1)
    int p1 = c >> 1;
    int p2 = p1 + 96;                      // z2 channels c+192, c+193
    float wA[18], wB[18];
#pragma unroll
    for (int k = 0; k < 18; ++k) {
        wA[k] = w_dw[(size_t)c*9 + k];
        wB[k] = w_dw[(size_t)(c+HID)*9 + k];
    }

    float accA[2][2][4], accB[2][2][4];    // [src][sub][px]
#pragma unroll
    for (int sx = 0; sx < 2; ++sx)
#pragma unroll
        for (int u = 0; u < 2; ++u)
#pragma unroll
            for (int j = 0; j < 4; ++j) { accA[sx][u][j]=0.f; accB[sx][u][j]=0.f; }

    auto ld = [&](int r, uint4& A, uint4& B) {
        int y = row0 - 1 + r;
        A = (uint4){0,0,0,0}; B = (uint4){0,0,0,0};
        if (y >= 0 && y < H_) {
            A = *(const uint4*)(zb + (size_t)p1*NPX + (size_t)y*W_ + cb);
            B = *(const uint4*)(zb + (size_t)p2*NPX + (size_t)y*W_ + cb);
        }
    };

    uint4 a_cur, b_cur;
    ld(0, a_cur, b_cur);
#pragma unroll
    for (int r = 0; r < DROWS + 2; ++r) {
        uint4 a_nxt, b_nxt;
        if (r < DROWS + 1) ld(r + 1, a_nxt, b_nxt);

        uint aL = (uint)__shfl_up((int)a_cur.w, 1, 64);  if (lane == 0)  aL = 0u;
        uint aR = (uint)__shfl_down((int)a_cur.x, 1, 64); if (lane == 63) aR = 0u;
        uint bL = (uint)__shfl_up((int)b_cur.w, 1, 64);  if (lane == 0)  bL = 0u;
        uint bR = (uint)__shfl_down((int)b_cur.x, 1, 64); if (lane == 63) bR = 0u;

        float dA[2][4], dB[2][4];
#pragma unroll
        for (int sub = 0; sub < 2; ++sub) {
            {   // src A (z1)
                float xv[6] = {extc(aL,sub), extc(a_cur.x,sub), extc(a_cur.y,sub),
                               extc(a_cur.z,sub), extc(a_cur.w,sub), extc(aR,sub)};
                const float* w = &wA[sub*9];
#pragma unroll
                for (int j = 0; j < 4; ++j) {
                    float h2 = fmaf(xv[j],w[6], fmaf(xv[j+1],w[7], xv[j+2]*w[8]));
                    float h1 = fmaf(xv[j],w[3], fmaf(xv[j+1],w[4], xv[j+2]*w[5]));
                    float h0 = fmaf(xv[j],w[0], fmaf(xv[j+1],w[1], xv[j+2]*w[2]));
                    dA[sub][j]    = accA[0][sub][j] + h2;
                    accA[0][sub][j] = accB[0][sub][j] + h1;
                    accB[0][sub][j] = h0;
                }
            }
            {   // src B (z2)
                float xv[6] = {extc(bL,sub), extc(b_cur.x,sub), extc(b_cur.y,sub),
                               extc(b_cur.z,sub), extc(b_cur.w,sub), extc(bR,sub)};
                const float* w = &wB[sub*9];
#pragma unroll
                for (int j = 0; j < 4; ++j) {
                    float h2 = fmaf(xv[j],w[6], fmaf(xv[j+1],w[7], xv[j+2]*w[8]));
                    float h1 = fmaf(xv[j],w[3], fmaf(xv[j+1],w[4], xv[j+2]*w[5]));
                    float h0 = fmaf(xv[j],w[0], fmaf(xv[j+1],w[1], xv[j+2]*w[2]));
                    dB[sub][j]    = accA[1][sub][j] + h2;
                    accA[1][sub][j] = accB[1][sub][j] + h1;
                    accB[1][sub][j] = h0;
                }
            }
        }

        if (r >= 2) {
            int o = row0 + r - 2;
            uint4 val;
            val.x = (uint)f2bf(gelu_f(dA[0][0]) * dB[0][0]) |
                    (((uint)f2bf(gelu_f(dA[1][0]) * dB[1][0])) << 16);
            val.y = (uint)f2bf(gelu_f(dA[0][1]) * dB[0][1]) |
                    (((uint)f2bf(gelu_f(dA[1][1]) * dB[1][1])) << 16);
            val.z = (uint)f2bf(gelu_f(dA[0][2]) * dB[0][2]) |
                    (((uint)f2bf(gelu_f(dA[1][2]) * dB[1][2])) << 16);
            val.w = (uint)f2bf(gelu_f(dA[0][3]) * dB[0][3]) |
                    (((uint)f2bf(gelu_f(dA[1][3]) * dB[1][3])) << 16);
            *(uint4*)(tb + (size_t)s * NPX + (size_t)o * W_ + cb) = val;
        }
        a_cur = a_nxt; b_cur = b_nxt;
    }
}

// ---------------------------------------------------------------------------
// B2 v2: GEMM2 via MFMA, 8 waves: wave = 48 oc x 64 px; tg read from planar
// packed slices (slice q -> frag word q).
// Grid: (256 rows, 1, nb); block = 512.
// ---------------------------------------------------------------------------
__global__ __launch_bounds__(512)
void gemm2_mfma(const uint* __restrict__ tg4,
                const ushort* __restrict__ whi, const ushort* __restrict__ wlo,
                float* __restrict__ out, int b0) {
    int t = threadIdx.x;
    int l = t & 63, wv = t >> 6;          // 8 waves
    int ocg = wv & 1, pxg = wv >> 1;      // 2 oc halves x 4 px groups
    int lm = l & 15, g4 = l >> 4;
    int h = blockIdx.x;
    int bg = blockIdx.z;
    int px0 = h * W_ + pxg*64;
    const uint* tb = tg4 + (size_t)bg * HID/2 * NPX;

    f32x4 acc[3][4];
#pragma unroll
    for (int mf = 0; mf < 3; ++mf)
#pragma unroll
        for (int nf = 0; nf < 4; ++nf) acc[mf][nf] = (f32x4){0.f,0.f,0.f,0.f};

#pragma unroll
    for (int kc = 0; kc < 6; ++kc) {
        int s0 = kc*16 + g4*4;
        bf16x8 bfr[4];
#pragma unroll
        for (int nf = 0; nf < 4; ++nf) {
            int px = px0 + nf*16 + lm;
            uint4 u;
            u.x = tb[(size_t)(s0+0)*NPX + px];
            u.y = tb[(size_t)(s0+1)*NPX + px];
            u.z = tb[(size_t)(s0+2)*NPX + px];
            u.w = tb[(size_t)(s0+3)*NPX + px];
            bf16x8 v; __builtin_memcpy(&v, &u, 16);
            bfr[nf] = v;
        }
        int k0 = kc*32 + g4*8;
#pragma unroll
        for (int mf = 0; mf < 3; ++mf) {
            int row = ocg*48 + mf*16 + lm;
            bf16x8 ah = *(const bf16x8*)(whi + (size_t)row*HID + k0);
            bf16x8 al = *(const bf16x8*)(wlo + (size_t)row*HID + k0);
#pragma unroll
            for (int nf = 0; nf < 4; ++nf) {
                acc[mf][nf] = __builtin_amdgcn_mfma_f32_16x16x32_bf16(ah, bfr[nf], acc[mf][nf], 0,0,0);
                acc[mf][nf] = __builtin_amdgcn_mfma_f32_16x16x32_bf16(al, bfr[nf], acc[mf][nf], 0,0,0);
            }
        }
    }
    float* ob = out + (size_t)(b0 + bg) * CIN * NPX;
#pragma unroll
    for (int mf = 0; mf < 3; ++mf)
#pragma unroll
        for (int nf = 0; nf < 4; ++nf)
#pragma unroll
            for (int r = 0; r < 4; ++r) {
                int oc = ocg*48 + mf*16 + g4*4 + r;
                ob[(size_t)oc * NPX + px0 + nf*16 + lm] = acc[mf][nf][r];
            }
}

// ---------------------------------------------------------------------------
extern "C" void kernel_launch(void* const* d_in, const int* in_sizes, int n_in,
                              void* d_out, int out_size, void* d_ws, size_t ws_size,
                              hipStream_t stream) {
    const float* x     = (const float*)d_in[0];
    const float* w_in  = (const float*)d_in[1];
    const float* w_dw  = (const float*)d_in[2];
    const float* fftw  = (const float*)d_in[3];
    const float* w_out = (const float*)d_in[4];
    float* out = (float*)d_out;

    char* ws = (char*)d_ws;
    ushort* whi_in  = (ushort*)(ws + 0);        //  73728
    ushort* wlo_in  = (ushort*)(ws + 73728);    //  73728
    ushort* whi_out = (ushort*)(ws + 147456);   //  36864
    ushort* wlo_out = (ushort*)(ws + 184320);   //  36864
    float*  g       = (float*) (ws + 221184);   //  98304
    int*    flags   = (int*)   (ws + 319488);   //   1536
    int*    allflag = (int*)   (ws + 321024);   //      4

    const size_t zoff   = 327680;
    const size_t zbytes = (size_t)HID * NPX * 4;     // 50331648 per batch (packed)
    const size_t tbytes = (size_t)(HID/2) * NPX * 4; // 25165824 per batch (planar)
    size_t avail = (ws_size > zoff) ? ws_size - zoff : 0;
    int nbg = (int)(avail / (zbytes + tbytes));
    if (nbg < 1) nbg = 1;
    if (nbg > B_) nbg = B_;
    uint* z4  = (uint*)(ws + zoff);
    uint* tg4 = (uint*)(ws + zoff + (size_t)nbg * zbytes);

    prep_gate<<<dim3(C2), dim3(64), 0, stream>>>(fftw, g, flags);
    reduce_flags<<<dim3(1), dim3(64), 0, stream>>>(flags, allflag);
    prep_w<<<dim3(216), dim3(256), 0, stream>>>(w_in, w_out,
                                                whi_in, wlo_in, whi_out, wlo_out);

    for (int b0 = 0; b0 < B_; b0 += nbg) {
        int nb = (B_ - b0 < nbg) ? (B_ - b0) : nbg;
        gemm1_mfma<<<dim3(NPX/64, nb), dim3(512), 0, stream>>>(x, whi_in, wlo_in, z4, b0);
        gate_fix<<<dim3(HP*WP, nb), dim3(256), 0, stream>>>(z4, g, flags, allflag);
        dw_gelu6<<<dim3(H_/DROWS/4, 96, nb), dim3(256), 0, stream>>>(z4, w_dw, tg4);
        gemm2_mfma<<<dim3(H_, 1, nb), dim3(512), 0, stream>>>(tg4, whi_out, wlo_out, out, b0);
    }
}